// Round 5
// baseline (211.923 us; speedup 1.0000x reference)
//
#include <hip/hip_runtime.h>
#include <math.h>

// B=2, T=2048, DIM=1024, H=16, HD=64. Inputs fp32, output fp32.
// R11: Vimg conflict-free V; scale+log2e folded into Q.  R12: VALU L-row.
// R13: read-first dbuf, 1 barrier/round (62->51).  R14: 2 qsets + XCD swz
// (FETCH 69.7->12.3MB, time flat).  R15: counted-vmcnt depth-2 (->49.3).
// Post-mortem R15: R13(16w/CU) == R15(8w/CU, 2x work/wave) ~= 50us with
// per-CU round work identical => throughput-limited. MfmaUtil 41 + VALU 32
// barely overlap at 2 waves/SIMD (both waves in same phase). 32x32x16 mfma
// = ~32 SIMD-cyc => MFMA demand alone is 42% of wall, matching MfmaUtil.
// R16: keep counted-vmcnt 3-parity pipeline, drop to 1 qset/wave, 32-key
// rounds (LDS 24KB/block) -> 4 blocks/CU = 4 waves/SIMD from INDEPENDENT
// blocks (own barriers, staggered phases) so MFMA of one wave overlaps
// EXP2/pack of another. vmcnt(2) steady-state, never 0 until last round.

typedef unsigned short u16;
typedef __attribute__((ext_vector_type(8))) short short8;
typedef __attribute__((ext_vector_type(4))) short short4v;
typedef __attribute__((ext_vector_type(4))) float f32x4;
typedef __attribute__((ext_vector_type(16))) float f32x16;

#define T_SEQ 2048

#if __has_builtin(__builtin_amdgcn_exp2f)
#define EXP2(x) __builtin_amdgcn_exp2f(x)
#else
#define EXP2(x) exp2f(x)
#endif

__device__ __forceinline__ float b2f(u16 u) {
    union { unsigned int i; float f; } x; x.i = ((unsigned int)u) << 16; return x.f;
}
__device__ __forceinline__ u16 f2b(float f) {
    union { float f; unsigned int i; } x; x.f = f;
    return (u16)((x.i + 0x7FFFu + ((x.i >> 16) & 1u)) >> 16);  // RNE
}
__device__ __forceinline__ void gl_lds16(const u16* g, u16* l) {
    __builtin_amdgcn_global_load_lds(
        (const __attribute__((address_space(1))) unsigned int*)g,
        (__attribute__((address_space(3))) unsigned int*)l, 16, 0, 0);
}
// pack 4 fp32 -> 4 bf16 (truncation; tiny bias, verified absmax ok)
__device__ __forceinline__ short4v pack4(float a, float b, float c, float d) {
    union { float f; unsigned int u; } xa, xb, xc, xd;
    xa.f = a; xb.f = b; xc.f = c; xd.f = d;
    union { unsigned int u2[2]; short4v s; } r;
    r.u2[0] = (xa.u >> 16) | (xb.u & 0xffff0000u);
    r.u2[1] = (xc.u >> 16) | (xd.u & 0xffff0000u);
    return r.s;
}

// ---------------------------------------------------------------------------
// Fused setup: [0,4096) cast x->bf16; [4096,7168) transpose Wqkv;
// [7168,8192) transpose Wout; [8192,8704) rope table.
// ---------------------------------------------------------------------------
__global__ __launch_bounds__(256) void setup_kernel(
    const float* __restrict__ x, const float* __restrict__ Wqkv,
    const float* __restrict__ Wout, u16* __restrict__ xb,
    u16* __restrict__ WqkvT, u16* __restrict__ WoutT,
    float* __restrict__ costab, float* __restrict__ sintab)
{
    const int bid = blockIdx.x;
    const int tid = threadIdx.x;

    if (bid < 4096) {
        int i = (bid * 256 + tid) * 4;
        float4 v = *(const float4*)(x + i);
        ushort4 w;
        w.x = f2b(v.x); w.y = f2b(v.y); w.z = f2b(v.z); w.w = f2b(v.w);
        *(ushort4*)(xb + i) = w;
        return;
    }
    if (bid < 8192) {
        const float* in; u16* out; int R, Cn, bx, by;
        if (bid < 7168) { in = Wqkv; out = WqkvT; R = 1024; Cn = 3072;
                          int id = bid - 4096; bx = id % 96; by = id / 96; }
        else            { in = Wout; out = WoutT; R = 1024; Cn = 1024;
                          int id = bid - 7168; bx = id & 31; by = id >> 5; }
        __shared__ u16 tile[32][33];
        const int tx = tid & 31, ty = tid >> 5;
        const int r0 = by * 32, c0 = bx * 32;
#pragma unroll
        for (int rr = ty; rr < 32; rr += 8)
            tile[tx][rr] = f2b(in[(size_t)(r0 + rr) * Cn + c0 + tx]);
        __syncthreads();
#pragma unroll
        for (int rr = ty; rr < 32; rr += 8)
            out[(size_t)(c0 + rr) * R + r0 + tx] = tile[rr][tx];
        return;
    }
    {
        int idx = (bid - 8192) * 256 + tid;
        int t = idx >> 6, d = idx & 63;
        const float nl32 = -0.28782313662425576f;   // -ln(10000)/32
        float f = __expf((float)(d & 31) * nl32);
        float s, c;
        __sincosf((float)t * f, &s, &c);
        costab[idx] = c; sintab[idx] = s;
    }
}

// ---------------------------------------------------------------------------
// MFMA GEMM (unchanged): C[M,N] = A @ Bt^T (+bias). OBF: bf16/fp32 out.
// ---------------------------------------------------------------------------
template<int OBF>
__global__ __launch_bounds__(256) void gemm_bt_mfma(
    const u16* __restrict__ A, const u16* __restrict__ Bt,
    void* __restrict__ Cv, const float* __restrict__ bias,
    int M, int N, int K)
{
    __shared__ u16 As[128 * 32];
    __shared__ u16 Bs[128 * 32];

    const int tid = threadIdx.x;
    const int wave = tid >> 6, lane = tid & 63;
    const int col = lane & 15, quad = lane >> 4;
    const int wm = (wave & 1) * 64, wn = (wave >> 1) * 64;
    const int m0 = blockIdx.y * 128, n0 = blockIdx.x * 128;

    f32x4 acc[4][4];
#pragma unroll
    for (int i = 0; i < 4; ++i)
#pragma unroll
        for (int j = 0; j < 4; ++j) acc[i][j] = f32x4{0.f, 0.f, 0.f, 0.f};

    const int c1 = tid, c2 = tid + 256;
    const u16* a1 = A + (size_t)(m0 + (c1 >> 2)) * K + (c1 & 3) * 8;
    const u16* a2 = A + (size_t)(m0 + (c2 >> 2)) * K + (c2 & 3) * 8;
    const u16* b1 = Bt + (size_t)(n0 + (c1 >> 2)) * K + (c1 & 3) * 8;
    const u16* b2 = Bt + (size_t)(n0 + (c2 >> 2)) * K + (c2 & 3) * 8;
    u16* la1 = As + c1 * 8; u16* la2 = As + c2 * 8;
    u16* lb1 = Bs + c1 * 8; u16* lb2 = Bs + c2 * 8;

    for (int k0 = 0; k0 < K; k0 += 32) {
        __syncthreads();
        gl_lds16(a1 + k0, la1);
        gl_lds16(a2 + k0, la2);
        gl_lds16(b1 + k0, lb1);
        gl_lds16(b2 + k0, lb2);
        __syncthreads();

        short8 af[4], bfr[4];
#pragma unroll
        for (int i = 0; i < 4; ++i) {
            af[i]  = *(const short8*)&As[(wm + i * 16 + col) * 32 + quad * 8];
            bfr[i] = *(const short8*)&Bs[(wn + i * 16 + col) * 32 + quad * 8];
        }
#pragma unroll
        for (int i = 0; i < 4; ++i)
#pragma unroll
            for (int j = 0; j < 4; ++j)
                acc[i][j] = __builtin_amdgcn_mfma_f32_16x16x32_bf16(
                    af[i], bfr[j], acc[i][j], 0, 0, 0);
    }

#pragma unroll
    for (int j = 0; j < 4; ++j) {
        int n = n0 + wn + j * 16 + col;
        float bv = bias ? bias[n] : 0.f;
#pragma unroll
        for (int i = 0; i < 4; ++i) {
            int mbase = m0 + wm + i * 16 + quad * 4;
#pragma unroll
            for (int r = 0; r < 4; ++r) {
                if (OBF) ((u16*)Cv)[(size_t)(mbase + r) * N + n] = f2b(acc[i][j][r] + bv);
                else     ((float*)Cv)[(size_t)(mbase + r) * N + n] = acc[i][j][r] + bv;
            }
        }
    }
}

// ---------------------------------------------------------------------------
// Prep: qkvb bf16 -> rope(q)*0.125*log2e, rope(k) head-major Qb/Kb[bh][t][64];
// V written as attn LDS-image Vimg[bh][kt][slot 0..255][8 u16] (R10-verified).
// ---------------------------------------------------------------------------
__global__ __launch_bounds__(256) void prep_kernel(
    const u16* __restrict__ qkvb, const float* __restrict__ costab,
    const float* __restrict__ sintab, u16* __restrict__ Qb,
    u16* __restrict__ Kb, u16* __restrict__ Vimg)
{
    __shared__ u16 Vls[64][72];

    const int tid = threadIdx.x;
    const int bh = blockIdx.y;
    const int t0 = blockIdx.x * 64;
    const int b = bh >> 4, h = bh & 15;
    const int t_loc = tid >> 2;
    const int d0 = (tid & 3) * 16;

    const int t = t0 + t_loc;
    const u16* qp = qkvb + ((size_t)(b * T_SEQ + t)) * 3072 + h * 64 + d0;

    float ct[16], st[16];
    {
        const float* cp = costab + (size_t)t * 64 + d0;
        const float* sp = sintab + (size_t)t * 64 + d0;
#pragma unroll
        for (int j = 0; j < 16; j += 4) {
            *(float4*)&ct[j] = *(const float4*)(cp + j);
            *(float4*)&st[j] = *(const float4*)(sp + j);
        }
    }

#pragma unroll
    for (int part = 0; part < 2; ++part) {
        // fold QK^T scale AND log2(e) into Q: p = 2^(s_scaled) in attn.
        const float sc = part ? 1.f : 0.18033688011112042f;  // 0.125*log2(e)
        const u16* src = qp + part * 1024;
        u16* dst = (part ? Kb : Qb) + ((size_t)(bh * T_SEQ + t)) * 64 + d0;
        short8 v0 = *(const short8*)(src);
        short8 v1 = *(const short8*)(src + 8);
        float f[16];
#pragma unroll
        for (int j = 0; j < 8; ++j) { f[j] = b2f((u16)v0[j]); f[8 + j] = b2f((u16)v1[j]); }
        u16 o[16];
#pragma unroll
        for (int i = 0; i < 8; ++i) {
            float e = f[2 * i], od = f[2 * i + 1];
            o[2 * i]     = f2b((e * ct[2 * i]      - od * st[2 * i]) * sc);
            o[2 * i + 1] = f2b((od * ct[2 * i + 1] + e  * st[2 * i + 1]) * sc);
        }
        *(short8*)(dst)     = *(short8*)&o[0];
        *(short8*)(dst + 8) = *(short8*)&o[8];
    }

    {
        const u16* src = qp + 2048;
        *(short8*)&Vls[t_loc][d0]     = *(const short8*)(src);
        *(short8*)&Vls[t_loc][d0 + 8] = *(const short8*)(src + 8);
    }
    __syncthreads();
    {
        const int dt    = tid >> 7;
        const int g     = (tid >> 5) & 3;
        const int hi2   = (tid >> 4) & 1;
        const int dpair = tid & 15;
        const int kl0 = g * 8 + hi2 * 4;
        const int d0v = dt * 32 + 2 * dpair;
        const int kt_base = blockIdx.x * 2;   // two 32-key tiles per block
#pragma unroll
        for (int ktl = 0; ktl < 2; ++ktl) {
            u16 o[8];
#pragma unroll
            for (int j = 0; j < 4; ++j) {
                o[j]     = Vls[ktl * 32 + kl0 + j][d0v];
                o[4 + j] = Vls[ktl * 32 + kl0 + j][d0v + 1];
            }
            u16* dst = Vimg + ((size_t)(bh * 64 + kt_base + ktl)) * 2048 + tid * 8;
            *(short8*)dst = *(short8*)&o[0];
        }
    }
}

// ---------------------------------------------------------------------------
// MFMA flash attention, S^T formulation, counted-vmcnt pipelined rounds of
// 32 keys. Wave = 32 q-rows (1 qset); block = 4 waves; grid 1024 = 4/CU
// (16 waves/CU = 4/SIMD, all from independent blocks -> staggered phases).
// 3 LDS parities (24KB), depth-2 prefetch, vmcnt(2) steady-state.
// ---------------------------------------------------------------------------
__global__ __launch_bounds__(256, 4) void attn32_kernel(
    const u16* __restrict__ Qb, const u16* __restrict__ Kb,
    const u16* __restrict__ Vimg, float* __restrict__ po, float* __restrict__ pl)
{
    __shared__ u16 Kbuf[3][2048];   // [parity][tile]  12 KB
    __shared__ u16 Vbuf[3][2048];   // 12 KB

    const int tid = threadIdx.x;
    const int wave = tid >> 6, lane = tid & 63;
    const int qcol = lane & 31;
    const int hi = lane >> 5;

    // XCD swizzle (grid 1024 = 8 XCDs x 128): each XCD gets a contiguous
    // 128-logical-block chunk = 4 bh K/V panels (2MB) resident in its L2.
    const int bid = blockIdx.x;
    const int lbid = (bid & 7) * 128 + (bid >> 3);
    const int bh = lbid >> 5;
    const int seg = (lbid >> 4) & 1;
    const int qblk = lbid & 15;
    const int qrow0 = qblk * 128 + wave * 32;

    // Q B-frags (32x32x16): lane(n=q, hi): Q[q][c*16 + hi*8 + j]
    short8 qa[4];
    {
        const u16* qp = Qb + ((size_t)(bh * T_SEQ + qrow0 + qcol)) * 64 + hi * 8;
#pragma unroll
        for (int c = 0; c < 4; ++c) qa[c] = *(const short8*)(qp + c * 16);
    }

    f32x16 O0, O1;
#pragma unroll
    for (int i = 0; i < 16; ++i) { O0[i] = 0.f; O1[i] = 0.f; }
    float Lacc = 0.f;

    const u16* kg_ptr = Kb + ((size_t)bh * T_SEQ + qcol) * 64 + wave * 16 + hi * 8;
    const u16* vg_ptr = Vimg + ((size_t)bh * 64) * 2048 + tid * 8;

    const int kt0 = seg * 32;

#define STAGE(p, rr) do {                                                     \
        gl_lds16(kg_ptr + (size_t)(kt0 + (rr)) * 2048, &Kbuf[p][tid * 8]);    \
        gl_lds16(vg_ptr + (size_t)(kt0 + (rr)) * 2048, &Vbuf[p][tid * 8]);    \
    } while (0)

    // prologue: rounds 0,1 in flight (4 DMAs/wave)
    STAGE(0, 0);
    STAGE(1, 1);

    int cur = 0, prv = 2;   // round r reads parity r%3; stages r+2 into (r+2)%3
    for (int r = 0; r < 32; ++r) {
        // own round-r DMAs landed (oldest 2); round r+1's 2 stay in flight
        if (r < 31) asm volatile("s_waitcnt vmcnt(2)" ::: "memory");
        else        asm volatile("s_waitcnt vmcnt(0)" ::: "memory");
        // all waves passed their wait => all slices of parity cur landed
        __builtin_amdgcn_s_barrier();
        asm volatile("" ::: "memory");          // compiler fence
        __builtin_amdgcn_sched_barrier(0);      // rule #18: pin MIR scheduler

        // (1) pull this round's K/V fragments into registers
        short8 kf[4];
        short4v vv[8];
#pragma unroll
        for (int f = 0; f < 4; ++f)
            kf[f] = *(const short8*)&Kbuf[cur][(f * 64 + lane) * 8];
#pragma unroll
        for (int g = 0; g < 4; ++g) {
            vv[2 * g]     = *(const short4v*)&Vbuf[cur][g * 256 + lane * 4];
            vv[2 * g + 1] = *(const short4v*)&Vbuf[cur][1024 + g * 256 + lane * 4];
        }

        // (2) stage round r+2 into parity prv (freed by this round's barrier)
        if (r < 30) STAGE(prv, r + 2);

        // (3) register-only compute
        f32x16 sT;
#pragma unroll
        for (int ii = 0; ii < 16; ++ii) sT[ii] = 0.f;
        __builtin_amdgcn_s_setprio(1);
#pragma unroll
        for (int c = 0; c < 4; ++c)
            sT = __builtin_amdgcn_mfma_f32_32x32x16_bf16(kf[c], qa[c], sT, 0, 0, 0);
        __builtin_amdgcn_s_setprio(0);

        float pe[16];
#pragma unroll
        for (int ii = 0; ii < 16; ++ii) pe[ii] = EXP2(sT[ii]);
        short4v pb[4];
#pragma unroll
        for (int g = 0; g < 4; ++g) {
            pb[g] = pack4(pe[4 * g + 0], pe[4 * g + 1],
                          pe[4 * g + 2], pe[4 * g + 3]);
            Lacc += (pe[4 * g + 0] + pe[4 * g + 1]) +
                    (pe[4 * g + 2] + pe[4 * g + 3]);
        }

        __builtin_amdgcn_s_setprio(1);
#pragma unroll
        for (int g = 0; g < 4; ++g) {
            O0 = __builtin_amdgcn_mfma_f32_32x32x8bf16_1k(vv[2 * g],     pb[g], O0, 0, 0, 0);
            O1 = __builtin_amdgcn_mfma_f32_32x32x8bf16_1k(vv[2 * g + 1], pb[g], O1, 0, 0, 0);
        }
        __builtin_amdgcn_s_setprio(0);

        prv = cur;
        cur = (cur == 2) ? 0 : cur + 1;
    }
#undef STAGE

    // combine L across the hi-half pair
    float Lq = Lacc + __shfl(Lacc, lane ^ 32);

    // epilogue: C col=q, row d_local=(r&3)+8*(r>>2)+4*hi; store fp32 partials
    const size_t prow = ((size_t)(seg * 32 + bh)) * T_SEQ + qrow0 + qcol;
    float* op = po + prow * 64;
#pragma unroll
    for (int g2 = 0; g2 < 4; ++g2) {
        int dd = g2 * 8 + hi * 4;
        *(float4*)(op + dd)      = make_float4(O0[4 * g2 + 0], O0[4 * g2 + 1],
                                               O0[4 * g2 + 2], O0[4 * g2 + 3]);
        *(float4*)(op + 32 + dd) = make_float4(O1[4 * g2 + 0], O1[4 * g2 + 1],
                                               O1[4 * g2 + 2], O1[4 * g2 + 3]);
    }
    if (hi == 0) pl[prow] = Lq;
}

// ---------------------------------------------------------------------------
// Combine: out = (O_s0 + O_s1) / (L_s0 + L_s1), write bf16 head-merged aob.
// ---------------------------------------------------------------------------
__global__ __launch_bounds__(256) void attn_combine_kernel(
    const float* __restrict__ po, const float* __restrict__ pl,
    u16* __restrict__ aob)
{
    const int idx = blockIdx.x * 256 + (int)threadIdx.x;
    const int row = idx >> 4;        // bh*2048 + t
    const int d4 = idx & 15;

    float4 o0 = *(const float4*)(po + (size_t)row * 64 + d4 * 4);
    float4 o1 = *(const float4*)(po + ((size_t)row + 65536) * 64 + d4 * 4);
    float L = pl[row] + pl[row + 65536];
    float inv = 1.f / L;

    const int bh = row >> 11, t = row & 2047;
    const int b = bh >> 4, h = bh & 15;
    ushort4 w;
    w.x = f2b((o0.x + o1.x) * inv);
    w.y = f2b((o0.y + o1.y) * inv);
    w.z = f2b((o0.z + o1.z) * inv);
    w.w = f2b((o0.w + o1.w) * inv);
    *(ushort4*)(aob + ((size_t)(b * T_SEQ + t)) * 1024 + h * 64 + d4 * 4) = w;
}

// ---------------------------------------------------------------------------
extern "C" void kernel_launch(void* const* d_in, const int* in_sizes, int n_in,
                              void* d_out, int out_size, void* d_ws, size_t ws_size,
                              hipStream_t stream)
{
    const float* x    = (const float*)d_in[0];
    const float* Wqkv = (const float*)d_in[1];
    const float* Wout = (const float*)d_in[2];
    const float* bout = (const float*)d_in[3];
    float* out = (float*)d_out;

    char* w = (char*)d_ws;
    u16* qkvb    = (u16*)(w);                   // 25,165,824  (dead after prep)
    u16* xb      = (u16*)(w + 25165824);        //  8,388,608  (dead after gemm1)
    u16* WqkvT   = (u16*)(w + 33554432);        //  6,291,456  (dead after gemm1)
    u16* WoutT   = (u16*)(w + 39845888);        //  2,097,152
    u16* aob     = (u16*)(w + 41943040);        //  8,388,608
    u16* Qb      = (u16*)(w + 50331648);        //  8,388,608
    u16* Kb      = (u16*)(w + 58720256);        //  8,388,608
    u16* Vimg    = (u16*)(w + 67108864);        //  8,388,608
    float* ctab  = (float*)(w + 75497472);      //    524,288
    float* stab  = (float*)(w + 76021760);      //    524,288
    // attn partials alias dead buffers (proven safe R8-R10):
    float* po    = (float*)(w);                 // 33,554,432 over qkvb+xb
    float* pl    = (float*)(w + 33554432);      //    524,288 over WqkvT

    dim3 blk(256);
    setup_kernel<<<dim3(8704), blk, 0, stream>>>(x, Wqkv, Wout, xb, WqkvT, WoutT, ctab, stab);
    gemm_bt_mfma<1><<<dim3(24, 32), blk, 0, stream>>>(xb, WqkvT, qkvb, nullptr, 4096, 3072, 1024);
    prep_kernel<<<dim3(32, 32), blk, 0, stream>>>(qkvb, ctab, stab, Qb, Kb, Vimg);
    attn32_kernel<<<dim3(1024), blk, 0, stream>>>(Qb, Kb, Vimg, po, pl);
    attn_combine_kernel<<<dim3(4096), blk, 0, stream>>>(po, pl, aob);
    gemm_bt_mfma<0><<<dim3(8, 32), blk, 0, stream>>>(aob, WoutT, out, bout, 4096, 1024, 1024);
}

// Round 7
// 199.167 us; speedup vs baseline: 1.0640x; 1.0640x over previous
//
#include <hip/hip_runtime.h>
#include <math.h>

// B=2, T=2048, DIM=1024, H=16, HD=64. Inputs fp32, output fp32.
// R11-R16 history: Vimg conflict-free V; VALU L-row; counted-vmcnt 3-parity
// pipeline; XCD swizzle (FETCH 69.7->12.3MB). R13/R15/R16 all ~50us with
// MfmaUtil pinned ~40% across occupancies 15-30% => per-wave MFMA pipe time
// is the binding term (PASS-limited 32x32x8bf16_1k: 8 passes for K=8).
// R17: (a) PV as 2x mfma_32x32x16 per d-block (K=16): pack pe pairs into
// W0..W7, v_permlane32_swap_b32 (W0,W2)(W1,W3) -> {W0..W3} = exact B-frag
// keys 0-15 for BOTH lane halves; {W4..W7} = keys 16-31 (derivation checked
// against m74/m101 C-layout). Vimg re-permuted so V A-frags are lane-linear
// b128 reads. MFMA/round 12 -> 8. (b) drop K-split: 64 rounds, grid 512,
// divide by L in-kernel, write bf16 aob directly (kills po + attn_combine).
// R18 (resubmit after infra failure): restore R13/R16's READ-FIRST order --
// LDS->reg pulls BEFORE the STAGE issue. R17 had STAGE first, which risks
// the compiler's conservative vmcnt(0) drain before aliasing ds_reads
// (m99/m100/R10 precedent) and would serialize every round.

typedef unsigned short u16;
typedef __attribute__((ext_vector_type(8))) short short8;
typedef __attribute__((ext_vector_type(4))) short short4v;
typedef __attribute__((ext_vector_type(4))) float f32x4;
typedef __attribute__((ext_vector_type(16))) float f32x16;

#define T_SEQ 2048

#if __has_builtin(__builtin_amdgcn_exp2f)
#define EXP2(x) __builtin_amdgcn_exp2f(x)
#else
#define EXP2(x) exp2f(x)
#endif

__device__ __forceinline__ float b2f(u16 u) {
    union { unsigned int i; float f; } x; x.i = ((unsigned int)u) << 16; return x.f;
}
__device__ __forceinline__ u16 f2b(float f) {
    union { float f; unsigned int i; } x; x.f = f;
    return (u16)((x.i + 0x7FFFu + ((x.i >> 16) & 1u)) >> 16);  // RNE
}
__device__ __forceinline__ void gl_lds16(const u16* g, u16* l) {
    __builtin_amdgcn_global_load_lds(
        (const __attribute__((address_space(1))) unsigned int*)g,
        (__attribute__((address_space(3))) unsigned int*)l, 16, 0, 0);
}
// pack 2 fp32 -> 1 u32 of 2 bf16 (truncation; tiny bias, verified absmax ok)
__device__ __forceinline__ unsigned int packpair(float a, float b) {
    union { float f; unsigned int u; } xa, xb; xa.f = a; xb.f = b;
    return (xa.u >> 16) | (xb.u & 0xffff0000u);
}

// ---------------------------------------------------------------------------
// Fused setup: [0,4096) cast x->bf16; [4096,7168) transpose Wqkv;
// [7168,8192) transpose Wout; [8192,8704) rope table.
// ---------------------------------------------------------------------------
__global__ __launch_bounds__(256) void setup_kernel(
    const float* __restrict__ x, const float* __restrict__ Wqkv,
    const float* __restrict__ Wout, u16* __restrict__ xb,
    u16* __restrict__ WqkvT, u16* __restrict__ WoutT,
    float* __restrict__ costab, float* __restrict__ sintab)
{
    const int bid = blockIdx.x;
    const int tid = threadIdx.x;

    if (bid < 4096) {
        int i = (bid * 256 + tid) * 4;
        float4 v = *(const float4*)(x + i);
        ushort4 w;
        w.x = f2b(v.x); w.y = f2b(v.y); w.z = f2b(v.z); w.w = f2b(v.w);
        *(ushort4*)(xb + i) = w;
        return;
    }
    if (bid < 8192) {
        const float* in; u16* out; int R, Cn, bx, by;
        if (bid < 7168) { in = Wqkv; out = WqkvT; R = 1024; Cn = 3072;
                          int id = bid - 4096; bx = id % 96; by = id / 96; }
        else            { in = Wout; out = WoutT; R = 1024; Cn = 1024;
                          int id = bid - 7168; bx = id & 31; by = id >> 5; }
        __shared__ u16 tile[32][33];
        const int tx = tid & 31, ty = tid >> 5;
        const int r0 = by * 32, c0 = bx * 32;
#pragma unroll
        for (int rr = ty; rr < 32; rr += 8)
            tile[tx][rr] = f2b(in[(size_t)(r0 + rr) * Cn + c0 + tx]);
        __syncthreads();
#pragma unroll
        for (int rr = ty; rr < 32; rr += 8)
            out[(size_t)(c0 + rr) * R + r0 + tx] = tile[rr][tx];
        return;
    }
    {
        int idx = (bid - 8192) * 256 + tid;
        int t = idx >> 6, d = idx & 63;
        const float nl32 = -0.28782313662425576f;   // -ln(10000)/32
        float f = __expf((float)(d & 31) * nl32);
        float s, c;
        __sincosf((float)t * f, &s, &c);
        costab[idx] = c; sintab[idx] = s;
    }
}

// ---------------------------------------------------------------------------
// MFMA GEMM (unchanged): C[M,N] = A @ Bt^T (+bias). OBF: bf16/fp32 out.
// ---------------------------------------------------------------------------
template<int OBF>
__global__ __launch_bounds__(256) void gemm_bt_mfma(
    const u16* __restrict__ A, const u16* __restrict__ Bt,
    void* __restrict__ Cv, const float* __restrict__ bias,
    int M, int N, int K)
{
    __shared__ u16 As[128 * 32];
    __shared__ u16 Bs[128 * 32];

    const int tid = threadIdx.x;
    const int wave = tid >> 6, lane = tid & 63;
    const int col = lane & 15, quad = lane >> 4;
    const int wm = (wave & 1) * 64, wn = (wave >> 1) * 64;
    const int m0 = blockIdx.y * 128, n0 = blockIdx.x * 128;

    f32x4 acc[4][4];
#pragma unroll
    for (int i = 0; i < 4; ++i)
#pragma unroll
        for (int j = 0; j < 4; ++j) acc[i][j] = f32x4{0.f, 0.f, 0.f, 0.f};

    const int c1 = tid, c2 = tid + 256;
    const u16* a1 = A + (size_t)(m0 + (c1 >> 2)) * K + (c1 & 3) * 8;
    const u16* a2 = A + (size_t)(m0 + (c2 >> 2)) * K + (c2 & 3) * 8;
    const u16* b1 = Bt + (size_t)(n0 + (c1 >> 2)) * K + (c1 & 3) * 8;
    const u16* b2 = Bt + (size_t)(n0 + (c2 >> 2)) * K + (c2 & 3) * 8;
    u16* la1 = As + c1 * 8; u16* la2 = As + c2 * 8;
    u16* lb1 = Bs + c1 * 8; u16* lb2 = Bs + c2 * 8;

    for (int k0 = 0; k0 < K; k0 += 32) {
        __syncthreads();
        gl_lds16(a1 + k0, la1);
        gl_lds16(a2 + k0, la2);
        gl_lds16(b1 + k0, lb1);
        gl_lds16(b2 + k0, lb2);
        __syncthreads();

        short8 af[4], bfr[4];
#pragma unroll
        for (int i = 0; i < 4; ++i) {
            af[i]  = *(const short8*)&As[(wm + i * 16 + col) * 32 + quad * 8];
            bfr[i] = *(const short8*)&Bs[(wn + i * 16 + col) * 32 + quad * 8];
        }
#pragma unroll
        for (int i = 0; i < 4; ++i)
#pragma unroll
            for (int j = 0; j < 4; ++j)
                acc[i][j] = __builtin_amdgcn_mfma_f32_16x16x32_bf16(
                    af[i], bfr[j], acc[i][j], 0, 0, 0);
    }

#pragma unroll
    for (int j = 0; j < 4; ++j) {
        int n = n0 + wn + j * 16 + col;
        float bv = bias ? bias[n] : 0.f;
#pragma unroll
        for (int i = 0; i < 4; ++i) {
            int mbase = m0 + wm + i * 16 + quad * 4;
#pragma unroll
            for (int r = 0; r < 4; ++r) {
                if (OBF) ((u16*)Cv)[(size_t)(mbase + r) * N + n] = f2b(acc[i][j][r] + bv);
                else     ((float*)Cv)[(size_t)(mbase + r) * N + n] = acc[i][j][r] + bv;
            }
        }
    }
}

// ---------------------------------------------------------------------------
// Prep: qkvb bf16 -> rope(q)*0.125*log2e, rope(k) head-major Qb/Kb[bh][t][64];
// V written as attn LDS-image for 32x32x16 A-frags (R17 layout):
// Vimg[bh][kt][slot tid*8+j] = V[k=(tid>>7)*16+((tid>>5)&1)*8+j][((tid>>6)&1)*32+(tid&31)]
// (lane reads one b128 = 8 consecutive keys for its dim column).
// ---------------------------------------------------------------------------
__global__ __launch_bounds__(256) void prep_kernel(
    const u16* __restrict__ qkvb, const float* __restrict__ costab,
    const float* __restrict__ sintab, u16* __restrict__ Qb,
    u16* __restrict__ Kb, u16* __restrict__ Vimg)
{
    __shared__ u16 Vls[64][72];

    const int tid = threadIdx.x;
    const int bh = blockIdx.y;
    const int t0 = blockIdx.x * 64;
    const int b = bh >> 4, h = bh & 15;
    const int t_loc = tid >> 2;
    const int d0 = (tid & 3) * 16;

    const int t = t0 + t_loc;
    const u16* qp = qkvb + ((size_t)(b * T_SEQ + t)) * 3072 + h * 64 + d0;

    float ct[16], st[16];
    {
        const float* cp = costab + (size_t)t * 64 + d0;
        const float* sp = sintab + (size_t)t * 64 + d0;
#pragma unroll
        for (int j = 0; j < 16; j += 4) {
            *(float4*)&ct[j] = *(const float4*)(cp + j);
            *(float4*)&st[j] = *(const float4*)(sp + j);
        }
    }

#pragma unroll
    for (int part = 0; part < 2; ++part) {
        // fold QK^T scale AND log2(e) into Q: p = 2^(s_scaled) in attn.
        const float sc = part ? 1.f : 0.18033688011112042f;  // 0.125*log2(e)
        const u16* src = qp + part * 1024;
        u16* dst = (part ? Kb : Qb) + ((size_t)(bh * T_SEQ + t)) * 64 + d0;
        short8 v0 = *(const short8*)(src);
        short8 v1 = *(const short8*)(src + 8);
        float f[16];
#pragma unroll
        for (int j = 0; j < 8; ++j) { f[j] = b2f((u16)v0[j]); f[8 + j] = b2f((u16)v1[j]); }
        u16 o[16];
#pragma unroll
        for (int i = 0; i < 8; ++i) {
            float e = f[2 * i], od = f[2 * i + 1];
            o[2 * i]     = f2b((e * ct[2 * i]      - od * st[2 * i]) * sc);
            o[2 * i + 1] = f2b((od * ct[2 * i + 1] + e  * st[2 * i + 1]) * sc);
        }
        *(short8*)(dst)     = *(short8*)&o[0];
        *(short8*)(dst + 8) = *(short8*)&o[8];
    }

    {
        const u16* src = qp + 2048;
        *(short8*)&Vls[t_loc][d0]     = *(const short8*)(src);
        *(short8*)&Vls[t_loc][d0 + 8] = *(const short8*)(src + 8);
    }
    __syncthreads();
    {
        // R17 region layout: region = tid>>6 = m_*2+db; m_ = key-half,
        // db = dim-half; h2 = A-frag hi, dv = dim-within-32.
        const int m_  = (tid >> 7) & 1;
        const int db  = (tid >> 6) & 1;
        const int h2  = (tid >> 5) & 1;
        const int dv  = tid & 31;
        const int k0v = m_ * 16 + h2 * 8;
        const int dcol = db * 32 + dv;
        const int kt_base = blockIdx.x * 2;   // two 32-key tiles per block
#pragma unroll
        for (int ktl = 0; ktl < 2; ++ktl) {
            u16 o[8];
#pragma unroll
            for (int j = 0; j < 8; ++j)
                o[j] = Vls[ktl * 32 + k0v + j][dcol];
            u16* dst = Vimg + ((size_t)(bh * 64 + kt_base + ktl)) * 2048 + tid * 8;
            *(short8*)dst = *(short8*)&o[0];
        }
    }
}

// ---------------------------------------------------------------------------
// MFMA flash attention, S^T formulation, counted-vmcnt pipelined rounds of
// 32 keys over the FULL sequence (64 rounds, no K-split). Wave = 32 q-rows;
// block = 4 waves = 128 q; grid 512 (32 bh x 16 qblk), XCD-swizzled.
// PV: P packed to bf16 W0..W7, 4x v_permlane32_swap_b32 -> two K=16 B-frags;
// 2x mfma_32x32x16 per d-block. Reads-first round order (R13-proven).
// Epilogue: O/L in-kernel, bf16 write straight to head-merged aob.
// ---------------------------------------------------------------------------
__global__ __launch_bounds__(256, 2) void attn32_kernel(
    const u16* __restrict__ Qb, const u16* __restrict__ Kb,
    const u16* __restrict__ Vimg, u16* __restrict__ aob)
{
    __shared__ u16 Kbuf[3][2048];   // [parity][tile]  12 KB
    __shared__ u16 Vbuf[3][2048];   // 12 KB

    const int tid = threadIdx.x;
    const int wave = tid >> 6, lane = tid & 63;
    const int qcol = lane & 31;
    const int hi = lane >> 5;

    // XCD swizzle (grid 512 = 8 XCDs x 64): each XCD gets a contiguous
    // 64-logical-block chunk = 4 bh K/V panels (~2MB) resident in its L2.
    const int bid = blockIdx.x;
    const int lbid = (bid & 7) * 64 + (bid >> 3);
    const int bh = lbid >> 4;
    const int qblk = lbid & 15;
    const int qrow0 = qblk * 128 + wave * 32;

    // Q B-frags (32x32x16): lane(n=q, hi): Q[q][c*16 + hi*8 + j]
    short8 qa[4];
    {
        const u16* qp = Qb + ((size_t)(bh * T_SEQ + qrow0 + qcol)) * 64 + hi * 8;
#pragma unroll
        for (int c = 0; c < 4; ++c) qa[c] = *(const short8*)(qp + c * 16);
    }

    f32x16 O0, O1;
#pragma unroll
    for (int i = 0; i < 16; ++i) { O0[i] = 0.f; O1[i] = 0.f; }
    float Lacc = 0.f;

    const u16* kg_ptr = Kb + ((size_t)bh * T_SEQ + qcol) * 64 + wave * 16 + hi * 8;
    const u16* vg_ptr = Vimg + ((size_t)bh * 64) * 2048 + tid * 8;

#define STAGE(p, rr) do {                                                     \
        gl_lds16(kg_ptr + (size_t)(rr) * 2048, &Kbuf[p][tid * 8]);            \
        gl_lds16(vg_ptr + (size_t)(rr) * 2048, &Vbuf[p][tid * 8]);            \
    } while (0)

    // prologue: rounds 0,1 in flight (4 DMAs/wave)
    STAGE(0, 0);
    STAGE(1, 1);

    int cur = 0, prv = 2;
    for (int r = 0; r < 64; ++r) {
        // own round-r DMAs landed (oldest 2); round r+1's 2 stay in flight
        if (r < 63) asm volatile("s_waitcnt vmcnt(2)" ::: "memory");
        else        asm volatile("s_waitcnt vmcnt(0)" ::: "memory");
        __builtin_amdgcn_s_barrier();
        asm volatile("" ::: "memory");          // compiler fence
        __builtin_amdgcn_sched_barrier(0);      // rule #18: pin MIR scheduler

        // (1) pull this round's K/V fragments into registers FIRST
        // (reads precede the new DMA issue -> no conservative vmcnt drain)
        short8 kf[4], vA[4];
#pragma unroll
        for (int f = 0; f < 4; ++f)
            kf[f] = *(const short8*)&Kbuf[cur][(f * 64 + lane) * 8];
#pragma unroll
        for (int rg = 0; rg < 4; ++rg)
            vA[rg] = *(const short8*)&Vbuf[cur][rg * 512 + lane * 8];

        // (2) stage round r+2 into parity prv (freed by this round's barrier)
        if (r < 62) STAGE(prv, r + 2);

        // (3) S^T = K * Q^T (scale/log2e pre-folded into Q)
        f32x16 sT;
#pragma unroll
        for (int ii = 0; ii < 16; ++ii) sT[ii] = 0.f;
        __builtin_amdgcn_s_setprio(1);
#pragma unroll
        for (int c = 0; c < 4; ++c)
            sT = __builtin_amdgcn_mfma_f32_32x32x16_bf16(kf[c], qa[c], sT, 0, 0, 0);
        __builtin_amdgcn_s_setprio(0);

        // p = 2^s; row-sum on VALU; pack pairs
        float pe[16];
#pragma unroll
        for (int ii = 0; ii < 16; ++ii) pe[ii] = EXP2(sT[ii]);
#pragma unroll
        for (int g = 0; g < 4; ++g)
            Lacc += (pe[4 * g + 0] + pe[4 * g + 1]) +
                    (pe[4 * g + 2] + pe[4 * g + 3]);

        unsigned int W0 = packpair(pe[0],  pe[1]);
        unsigned int W1 = packpair(pe[2],  pe[3]);
        unsigned int W2 = packpair(pe[4],  pe[5]);
        unsigned int W3 = packpair(pe[6],  pe[7]);
        unsigned int W4 = packpair(pe[8],  pe[9]);
        unsigned int W5 = packpair(pe[10], pe[11]);
        unsigned int W6 = packpair(pe[12], pe[13]);
        unsigned int W7 = packpair(pe[14], pe[15]);

        // cross-half exchange: after swap, {W0..W3} = B-frag keys 0-15 and
        // {W4..W7} = keys 16-31 for BOTH lane halves (row-mapped derivation).
        asm volatile("v_permlane32_swap_b32 %0, %1" : "+v"(W0), "+v"(W2));
        asm volatile("v_permlane32_swap_b32 %0, %1" : "+v"(W1), "+v"(W3));
        asm volatile("v_permlane32_swap_b32 %0, %1" : "+v"(W4), "+v"(W6));
        asm volatile("v_permlane32_swap_b32 %0, %1" : "+v"(W5), "+v"(W7));

        union FU { unsigned int u[4]; short8 s; } f0, f1;
        f0.u[0] = W0; f0.u[1] = W1; f0.u[2] = W2; f0.u[3] = W3;
        f1.u[0] = W4; f1.u[1] = W5; f1.u[2] = W6; f1.u[3] = W7;

        // O^T += V^T * P^T : 4x mfma 32x32x16 (regions rg = m_*2+db)
        __builtin_amdgcn_s_setprio(1);
        O0 = __builtin_amdgcn_mfma_f32_32x32x16_bf16(vA[0], f0.s, O0, 0, 0, 0);
        O1 = __builtin_amdgcn_mfma_f32_32x32x16_bf16(vA[1], f0.s, O1, 0, 0, 0);
        O0 = __builtin_amdgcn_mfma_f32_32x32x16_bf16(vA[2], f1.s, O0, 0, 0, 0);
        O1 = __builtin_amdgcn_mfma_f32_32x32x16_bf16(vA[3], f1.s, O1, 0, 0, 0);
        __builtin_amdgcn_s_setprio(0);

        prv = cur;
        cur = (cur == 2) ? 0 : cur + 1;
    }
#undef STAGE

    // combine L across the hi-half pair; divide and store bf16 directly
    float Lq = Lacc + __shfl(Lacc, lane ^ 32);
    float inv = 1.f / Lq;

    const int b = bh >> 4, h = bh & 15;
    u16* ab = aob + ((size_t)(b * T_SEQ + qrow0 + qcol)) * 1024 + h * 64;
#pragma unroll
    for (int g2 = 0; g2 < 4; ++g2) {
        int dd = g2 * 8 + hi * 4;
        ushort4 w0, w1;
        w0.x = f2b(O0[4 * g2 + 0] * inv); w0.y = f2b(O0[4 * g2 + 1] * inv);
        w0.z = f2b(O0[4 * g2 + 2] * inv); w0.w = f2b(O0[4 * g2 + 3] * inv);
        w1.x = f2b(O1[4 * g2 + 0] * inv); w1.y = f2b(O1[4 * g2 + 1] * inv);
        w1.z = f2b(O1[4 * g2 + 2] * inv); w1.w = f2b(O1[4 * g2 + 3] * inv);
        *(ushort4*)(ab + dd)      = w0;
        *(ushort4*)(ab + 32 + dd) = w1;
    }
}

// ---------------------------------------------------------------------------
extern "C" void kernel_launch(void* const* d_in, const int* in_sizes, int n_in,
                              void* d_out, int out_size, void* d_ws, size_t ws_size,
                              hipStream_t stream)
{
    const float* x    = (const float*)d_in[0];
    const float* Wqkv = (const float*)d_in[1];
    const float* Wout = (const float*)d_in[2];
    const float* bout = (const float*)d_in[3];
    float* out = (float*)d_out;

    char* w = (char*)d_ws;
    u16* qkvb    = (u16*)(w);                   // 25,165,824  (dead after prep)
    u16* xb      = (u16*)(w + 25165824);        //  8,388,608  (dead after gemm1)
    u16* WqkvT   = (u16*)(w + 33554432);        //  6,291,456  (dead after gemm1)
    u16* WoutT   = (u16*)(w + 39845888);        //  2,097,152
    u16* aob     = (u16*)(w + 41943040);        //  8,388,608
    u16* Qb      = (u16*)(w + 50331648);        //  8,388,608
    u16* Kb      = (u16*)(w + 58720256);        //  8,388,608
    u16* Vimg    = (u16*)(w + 67108864);        //  8,388,608
    float* ctab  = (float*)(w + 75497472);      //    524,288
    float* stab  = (float*)(w + 76021760);      //    524,288

    dim3 blk(256);
    setup_kernel<<<dim3(8704), blk, 0, stream>>>(x, Wqkv, Wout, xb, WqkvT, WoutT, ctab, stab);
    gemm_bt_mfma<1><<<dim3(24, 32), blk, 0, stream>>>(xb, WqkvT, qkvb, nullptr, 4096, 3072, 1024);
    prep_kernel<<<dim3(32, 32), blk, 0, stream>>>(qkvb, ctab, stab, Qb, Kb, Vimg);
    attn32_kernel<<<dim3(512), blk, 0, stream>>>(Qb, Kb, Vimg, aob);
    gemm_bt_mfma<0><<<dim3(8, 32), blk, 0, stream>>>(aob, WoutT, out, bout, 4096, 1024, 1024);
}

// Round 12
// 189.864 us; speedup vs baseline: 1.1162x; 1.0490x over previous
//
#include <hip/hip_runtime.h>
#include <math.h>

// B=2, T=2048, DIM=1024, H=16, HD=64. Inputs fp32, output fp32.
// R11-R18: attn rebuilt (Vimg, VALU L-row, counted-vmcnt 3-parity pipeline,
// XCD swizzle, K=16 PV via permlane32_swap, no K-split, direct bf16
// epilogue). Total 223 -> 199us; attn out of top-5; gemm1 now #1 (52.9us,
// MfmaUtil 18%, WRITE 60.6MB vs 25.2 ideal -> write-allocate RMW from u16
// scattered stores, 2-barrier vmcnt(0)-drain k-loop).
// R19: ported the attn-proven schedule to the GEMM: (a) counted-vmcnt
// 3-parity pipeline, read-first, vmcnt(4) steady state; (b) OBF=1 epilogue
// via LDS bounce -> contiguous per-thread global writes, no RMW.
// R20 BUGFIX: R19's bounce copy used short4v (4 u16 = 8B) but advanced 8
// u16 per step -> only half of each row written (absmax 0.24). Fix: short8
// (8 u16 = 16B) x8 covers the thread's full 64 u16. Pad 132 -> 136 so the
// row stride (272B = 17*16) keeps b128 copies 16B-aligned.
// R21/R22: byte-identical resubmits after infra failures (audit verified:
// coverage, alignment, vmcnt accounting, barrier uniformity, LDS aliasing,
// and all global accesses in-bounds at extremes -- no fault possible).
// R23: semantically identical resubmit; this comment line only changes the
// source hash in case the harness caches a poisoned artifact per-hash.

typedef unsigned short u16;
typedef __attribute__((ext_vector_type(8))) short short8;
typedef __attribute__((ext_vector_type(4))) short short4v;
typedef __attribute__((ext_vector_type(4))) float f32x4;
typedef __attribute__((ext_vector_type(16))) float f32x16;

#define T_SEQ 2048

#if __has_builtin(__builtin_amdgcn_exp2f)
#define EXP2(x) __builtin_amdgcn_exp2f(x)
#else
#define EXP2(x) exp2f(x)
#endif

__device__ __forceinline__ float b2f(u16 u) {
    union { unsigned int i; float f; } x; x.i = ((unsigned int)u) << 16; return x.f;
}
__device__ __forceinline__ u16 f2b(float f) {
    union { float f; unsigned int i; } x; x.f = f;
    return (u16)((x.i + 0x7FFFu + ((x.i >> 16) & 1u)) >> 16);  // RNE
}
__device__ __forceinline__ void gl_lds16(const u16* g, u16* l) {
    __builtin_amdgcn_global_load_lds(
        (const __attribute__((address_space(1))) unsigned int*)g,
        (__attribute__((address_space(3))) unsigned int*)l, 16, 0, 0);
}
// pack 2 fp32 -> 1 u32 of 2 bf16 (truncation; tiny bias, verified absmax ok)
__device__ __forceinline__ unsigned int packpair(float a, float b) {
    union { float f; unsigned int u; } xa, xb; xa.f = a; xb.f = b;
    return (xa.u >> 16) | (xb.u & 0xffff0000u);
}

// ---------------------------------------------------------------------------
// Fused setup: [0,4096) cast x->bf16; [4096,7168) transpose Wqkv;
// [7168,8192) transpose Wout; [8192,8704) rope table.
// ---------------------------------------------------------------------------
__global__ __launch_bounds__(256) void setup_kernel(
    const float* __restrict__ x, const float* __restrict__ Wqkv,
    const float* __restrict__ Wout, u16* __restrict__ xb,
    u16* __restrict__ WqkvT, u16* __restrict__ WoutT,
    float* __restrict__ costab, float* __restrict__ sintab)
{
    const int bid = blockIdx.x;
    const int tid = threadIdx.x;

    if (bid < 4096) {
        int i = (bid * 256 + tid) * 4;
        float4 v = *(const float4*)(x + i);
        ushort4 w;
        w.x = f2b(v.x); w.y = f2b(v.y); w.z = f2b(v.z); w.w = f2b(v.w);
        *(ushort4*)(xb + i) = w;
        return;
    }
    if (bid < 8192) {
        const float* in; u16* out; int R, Cn, bx, by;
        if (bid < 7168) { in = Wqkv; out = WqkvT; R = 1024; Cn = 3072;
                          int id = bid - 4096; bx = id % 96; by = id / 96; }
        else            { in = Wout; out = WoutT; R = 1024; Cn = 1024;
                          int id = bid - 7168; bx = id & 31; by = id >> 5; }
        __shared__ u16 tile[32][33];
        const int tx = tid & 31, ty = tid >> 5;
        const int r0 = by * 32, c0 = bx * 32;
#pragma unroll
        for (int rr = ty; rr < 32; rr += 8)
            tile[tx][rr] = f2b(in[(size_t)(r0 + rr) * Cn + c0 + tx]);
        __syncthreads();
#pragma unroll
        for (int rr = ty; rr < 32; rr += 8)
            out[(size_t)(c0 + rr) * R + r0 + tx] = tile[rr][tx];
        return;
    }
    {
        int idx = (bid - 8192) * 256 + tid;
        int t = idx >> 6, d = idx & 63;
        const float nl32 = -0.28782313662425576f;   // -ln(10000)/32
        float f = __expf((float)(d & 31) * nl32);
        float s, c;
        __sincosf((float)t * f, &s, &c);
        costab[idx] = c; sintab[idx] = s;
    }
}

// ---------------------------------------------------------------------------
// MFMA GEMM, counted-vmcnt 3-parity pipeline (R19): C[M,N] = A @ Bt^T (+bias).
// OBF=1: bf16 out via LDS-bounce coalesced epilogue. OBF=0: fp32 out direct.
// ---------------------------------------------------------------------------
template<int OBF>
__global__ __launch_bounds__(256) void gemm_bt_mfma(
    const u16* __restrict__ A, const u16* __restrict__ Bt,
    void* __restrict__ Cv, const float* __restrict__ bias,
    int M, int N, int K)
{
    __shared__ u16 sbuf[24576];   // 48 KB: As parities [0,12288), Bs [12288,24576)
    u16* const As0 = sbuf;
    u16* const Bs0 = sbuf + 12288;

    const int tid = threadIdx.x;
    const int wave = tid >> 6, lane = tid & 63;
    const int col = lane & 15, quad = lane >> 4;
    const int wm = (wave & 1) * 64, wn = (wave >> 1) * 64;
    const int m0 = blockIdx.y * 128, n0 = blockIdx.x * 128;

    f32x4 acc[4][4];
#pragma unroll
    for (int i = 0; i < 4; ++i)
#pragma unroll
        for (int j = 0; j < 4; ++j) acc[i][j] = f32x4{0.f, 0.f, 0.f, 0.f};

    const int c1 = tid, c2 = tid + 256;
    const u16* a1 = A + (size_t)(m0 + (c1 >> 2)) * K + (c1 & 3) * 8;
    const u16* a2 = A + (size_t)(m0 + (c2 >> 2)) * K + (c2 & 3) * 8;
    const u16* b1 = Bt + (size_t)(n0 + (c1 >> 2)) * K + (c1 & 3) * 8;
    const u16* b2 = Bt + (size_t)(n0 + (c2 >> 2)) * K + (c2 & 3) * 8;
    const int l1 = c1 * 8, l2 = c2 * 8;

#define GST(p, ks) do { const int k0_ = (ks) * 32;                            \
        gl_lds16(a1 + k0_, As0 + (p) * 4096 + l1);                            \
        gl_lds16(a2 + k0_, As0 + (p) * 4096 + l2);                            \
        gl_lds16(b1 + k0_, Bs0 + (p) * 4096 + l1);                            \
        gl_lds16(b2 + k0_, Bs0 + (p) * 4096 + l2);                            \
    } while (0)

    const int NK = K >> 5;
    // prologue: k-steps 0,1 in flight (8 DMAs/wave)
    GST(0, 0);
    GST(1, 1);

    int cur = 0, prv = 2;
    for (int ks = 0; ks < NK; ++ks) {
        // own k-step's 4 DMAs landed (oldest); next step's 4 stay in flight
        if (ks < NK - 1) asm volatile("s_waitcnt vmcnt(4)" ::: "memory");
        else             asm volatile("s_waitcnt vmcnt(0)" ::: "memory");
        __builtin_amdgcn_s_barrier();
        asm volatile("" ::: "memory");          // compiler fence
        __builtin_amdgcn_sched_barrier(0);      // rule #18: pin MIR scheduler

        // (1) read-first: pull fragments from parity cur
        short8 af[4], bfr[4];
        const u16* Ap = As0 + cur * 4096;
        const u16* Bp = Bs0 + cur * 4096;
#pragma unroll
        for (int i = 0; i < 4; ++i) {
            af[i]  = *(const short8*)&Ap[(wm + i * 16 + col) * 32 + quad * 8];
            bfr[i] = *(const short8*)&Bp[(wn + i * 16 + col) * 32 + quad * 8];
        }

        // (2) stage k-step ks+2 into parity prv (freed by this barrier)
        if (ks < NK - 2) GST(prv, ks + 2);

        // (3) register-only MFMA
        __builtin_amdgcn_s_setprio(1);
#pragma unroll
        for (int i = 0; i < 4; ++i)
#pragma unroll
            for (int j = 0; j < 4; ++j)
                acc[i][j] = __builtin_amdgcn_mfma_f32_16x16x32_bf16(
                    af[i], bfr[j], acc[i][j], 0, 0, 0);
        __builtin_amdgcn_s_setprio(0);

        prv = cur;
        cur = (cur == 2) ? 0 : cur + 1;
    }
#undef GST

    if (OBF) {
        // bf16 out: bounce through LDS ([128][136] u16; stride 272B = 17*16
        // keeps b128 accesses aligned and breaks power-of-2 bank aliasing),
        // then 128B contiguous per thread -> full-line HBM writes, no RMW.
        __syncthreads();
        u16* Cs = sbuf;   // 128*136*2 = 34816 B of the 48 KB
#pragma unroll
        for (int j = 0; j < 4; ++j) {
            const int cl = wn + j * 16 + col;
            const float bv = bias ? bias[n0 + cl] : 0.f;
#pragma unroll
            for (int i = 0; i < 4; ++i) {
                const int rl = wm + i * 16 + quad * 4;
#pragma unroll
                for (int r = 0; r < 4; ++r)
                    Cs[(rl + r) * 136 + cl] = f2b(acc[i][j][r] + bv);
            }
        }
        __syncthreads();
        // thread t owns row = t>>1, half = t&1: 64 contiguous u16 (128B)
        const int row = tid >> 1, half = tid & 1;
        const u16* src = Cs + row * 136 + half * 64;
        u16* dst = (u16*)Cv + (size_t)(m0 + row) * N + n0 + half * 64;
#pragma unroll
        for (int s = 0; s < 8; ++s)
            *(short8*)(dst + s * 8) = *(const short8*)(src + s * 8);
    } else {
        // fp32 out: direct stores (64B per 16 lanes, line-friendly) + bias
#pragma unroll
        for (int j = 0; j < 4; ++j) {
            int n = n0 + wn + j * 16 + col;
            float bv = bias ? bias[n] : 0.f;
#pragma unroll
            for (int i = 0; i < 4; ++i) {
                int mbase = m0 + wm + i * 16 + quad * 4;
#pragma unroll
                for (int r = 0; r < 4; ++r)
                    ((float*)Cv)[(size_t)(mbase + r) * N + n] = acc[i][j][r] + bv;
            }
        }
    }
}

// ---------------------------------------------------------------------------
// Prep: qkvb bf16 -> rope(q)*0.125*log2e, rope(k) head-major Qb/Kb[bh][t][64];
// V written as attn LDS-image for 32x32x16 A-frags (R17 layout).
// ---------------------------------------------------------------------------
__global__ __launch_bounds__(256) void prep_kernel(
    const u16* __restrict__ qkvb, const float* __restrict__ costab,
    const float* __restrict__ sintab, u16* __restrict__ Qb,
    u16* __restrict__ Kb, u16* __restrict__ Vimg)
{
    __shared__ u16 Vls[64][72];

    const int tid = threadIdx.x;
    const int bh = blockIdx.y;
    const int t0 = blockIdx.x * 64;
    const int b = bh >> 4, h = bh & 15;
    const int t_loc = tid >> 2;
    const int d0 = (tid & 3) * 16;

    const int t = t0 + t_loc;
    const u16* qp = qkvb + ((size_t)(b * T_SEQ + t)) * 3072 + h * 64 + d0;

    float ct[16], st[16];
    {
        const float* cp = costab + (size_t)t * 64 + d0;
        const float* sp = sintab + (size_t)t * 64 + d0;
#pragma unroll
        for (int j = 0; j < 16; j += 4) {
            *(float4*)&ct[j] = *(const float4*)(cp + j);
            *(float4*)&st[j] = *(const float4*)(sp + j);
        }
    }

#pragma unroll
    for (int part = 0; part < 2; ++part) {
        // fold QK^T scale AND log2(e) into Q: p = 2^(s_scaled) in attn.
        const float sc = part ? 1.f : 0.18033688011112042f;  // 0.125*log2(e)
        const u16* src = qp + part * 1024;
        u16* dst = (part ? Kb : Qb) + ((size_t)(bh * T_SEQ + t)) * 64 + d0;
        short8 v0 = *(const short8*)(src);
        short8 v1 = *(const short8*)(src + 8);
        float f[16];
#pragma unroll
        for (int j = 0; j < 8; ++j) { f[j] = b2f((u16)v0[j]); f[8 + j] = b2f((u16)v1[j]); }
        u16 o[16];
#pragma unroll
        for (int i = 0; i < 8; ++i) {
            float e = f[2 * i], od = f[2 * i + 1];
            o[2 * i]     = f2b((e * ct[2 * i]      - od * st[2 * i]) * sc);
            o[2 * i + 1] = f2b((od * ct[2 * i + 1] + e  * st[2 * i + 1]) * sc);
        }
        *(short8*)(dst)     = *(short8*)&o[0];
        *(short8*)(dst + 8) = *(short8*)&o[8];
    }

    {
        const u16* src = qp + 2048;
        *(short8*)&Vls[t_loc][d0]     = *(const short8*)(src);
        *(short8*)&Vls[t_loc][d0 + 8] = *(const short8*)(src + 8);
    }
    __syncthreads();
    {
        // R17 region layout: region = tid>>6 = m_*2+db; m_ = key-half,
        // db = dim-half; h2 = A-frag hi, dv = dim-within-32.
        const int m_  = (tid >> 7) & 1;
        const int db  = (tid >> 6) & 1;
        const int h2  = (tid >> 5) & 1;
        const int dv  = tid & 31;
        const int k0v = m_ * 16 + h2 * 8;
        const int dcol = db * 32 + dv;
        const int kt_base = blockIdx.x * 2;   // two 32-key tiles per block
#pragma unroll
        for (int ktl = 0; ktl < 2; ++ktl) {
            u16 o[8];
#pragma unroll
            for (int j = 0; j < 8; ++j)
                o[j] = Vls[ktl * 32 + k0v + j][dcol];
            u16* dst = Vimg + ((size_t)(bh * 64 + kt_base + ktl)) * 2048 + tid * 8;
            *(short8*)dst = *(short8*)&o[0];
        }
    }
}

// ---------------------------------------------------------------------------
// MFMA flash attention (R18, unchanged): S^T formulation, counted-vmcnt
// 3-parity pipeline, 64 rounds of 32 keys, K=16 PV via permlane32_swap,
// grid 512 XCD-swizzled, direct bf16 epilogue into head-merged aob.
// ---------------------------------------------------------------------------
__global__ __launch_bounds__(256, 2) void attn32_kernel(
    const u16* __restrict__ Qb, const u16* __restrict__ Kb,
    const u16* __restrict__ Vimg, u16* __restrict__ aob)
{
    __shared__ u16 Kbuf[3][2048];   // [parity][tile]  12 KB
    __shared__ u16 Vbuf[3][2048];   // 12 KB

    const int tid = threadIdx.x;
    const int wave = tid >> 6, lane = tid & 63;
    const int qcol = lane & 31;
    const int hi = lane >> 5;

    const int bid = blockIdx.x;
    const int lbid = (bid & 7) * 64 + (bid >> 3);
    const int bh = lbid >> 4;
    const int qblk = lbid & 15;
    const int qrow0 = qblk * 128 + wave * 32;

    // Q B-frags (32x32x16): lane(n=q, hi): Q[q][c*16 + hi*8 + j]
    short8 qa[4];
    {
        const u16* qp = Qb + ((size_t)(bh * T_SEQ + qrow0 + qcol)) * 64 + hi * 8;
#pragma unroll
        for (int c = 0; c < 4; ++c) qa[c] = *(const short8*)(qp + c * 16);
    }

    f32x16 O0, O1;
#pragma unroll
    for (int i = 0; i < 16; ++i) { O0[i] = 0.f; O1[i] = 0.f; }
    float Lacc = 0.f;

    const u16* kg_ptr = Kb + ((size_t)bh * T_SEQ + qcol) * 64 + wave * 16 + hi * 8;
    const u16* vg_ptr = Vimg + ((size_t)bh * 64) * 2048 + tid * 8;

#define STAGE(p, rr) do {                                                     \
        gl_lds16(kg_ptr + (size_t)(rr) * 2048, &Kbuf[p][tid * 8]);            \
        gl_lds16(vg_ptr + (size_t)(rr) * 2048, &Vbuf[p][tid * 8]);            \
    } while (0)

    STAGE(0, 0);
    STAGE(1, 1);

    int cur = 0, prv = 2;
    for (int r = 0; r < 64; ++r) {
        if (r < 63) asm volatile("s_waitcnt vmcnt(2)" ::: "memory");
        else        asm volatile("s_waitcnt vmcnt(0)" ::: "memory");
        __builtin_amdgcn_s_barrier();
        asm volatile("" ::: "memory");          // compiler fence
        __builtin_amdgcn_sched_barrier(0);      // rule #18

        // (1) read-first
        short8 kf[4], vA[4];
#pragma unroll
        for (int f = 0; f < 4; ++f)
            kf[f] = *(const short8*)&Kbuf[cur][(f * 64 + lane) * 8];
#pragma unroll
        for (int rg = 0; rg < 4; ++rg)
            vA[rg] = *(const short8*)&Vbuf[cur][rg * 512 + lane * 8];

        // (2) stage round r+2
        if (r < 62) STAGE(prv, r + 2);

        // (3) S^T = K * Q^T
        f32x16 sT;
#pragma unroll
        for (int ii = 0; ii < 16; ++ii) sT[ii] = 0.f;
        __builtin_amdgcn_s_setprio(1);
#pragma unroll
        for (int c = 0; c < 4; ++c)
            sT = __builtin_amdgcn_mfma_f32_32x32x16_bf16(kf[c], qa[c], sT, 0, 0, 0);
        __builtin_amdgcn_s_setprio(0);

        float pe[16];
#pragma unroll
        for (int ii = 0; ii < 16; ++ii) pe[ii] = EXP2(sT[ii]);
#pragma unroll
        for (int g = 0; g < 4; ++g)
            Lacc += (pe[4 * g + 0] + pe[4 * g + 1]) +
                    (pe[4 * g + 2] + pe[4 * g + 3]);

        unsigned int W0 = packpair(pe[0],  pe[1]);
        unsigned int W1 = packpair(pe[2],  pe[3]);
        unsigned int W2 = packpair(pe[4],  pe[5]);
        unsigned int W3 = packpair(pe[6],  pe[7]);
        unsigned int W4 = packpair(pe[8],  pe[9]);
        unsigned int W5 = packpair(pe[10], pe[11]);
        unsigned int W6 = packpair(pe[12], pe[13]);
        unsigned int W7 = packpair(pe[14], pe[15]);

        asm volatile("v_permlane32_swap_b32 %0, %1" : "+v"(W0), "+v"(W2));
        asm volatile("v_permlane32_swap_b32 %0, %1" : "+v"(W1), "+v"(W3));
        asm volatile("v_permlane32_swap_b32 %0, %1" : "+v"(W4), "+v"(W6));
        asm volatile("v_permlane32_swap_b32 %0, %1" : "+v"(W5), "+v"(W7));

        union FU { unsigned int u[4]; short8 s; } f0, f1;
        f0.u[0] = W0; f0.u[1] = W1; f0.u[2] = W2; f0.u[3] = W3;
        f1.u[0] = W4; f1.u[1] = W5; f1.u[2] = W6; f1.u[3] = W7;

        __builtin_amdgcn_s_setprio(1);
        O0 = __builtin_amdgcn_mfma_f32_32x32x16_bf16(vA[0], f0.s, O0, 0, 0, 0);
        O1 = __builtin_amdgcn_mfma_f32_32x32x16_bf16(vA[1], f0.s, O1, 0, 0, 0);
        O0 = __builtin_amdgcn_mfma_f32_32x32x16_bf16(vA[2], f1.s, O0, 0, 0, 0);
        O1 = __builtin_amdgcn_mfma_f32_32x32x16_bf16(vA[3], f1.s, O1, 0, 0, 0);
        __builtin_amdgcn_s_setprio(0);

        prv = cur;
        cur = (cur == 2) ? 0 : cur + 1;
    }
#undef STAGE

    float Lq = Lacc + __shfl(Lacc, lane ^ 32);
    float inv = 1.f / Lq;

    const int b = bh >> 4, h = bh & 15;
    u16* ab = aob + ((size_t)(b * T_SEQ + qrow0 + qcol)) * 1024 + h * 64;
#pragma unroll
    for (int g2 = 0; g2 < 4; ++g2) {
        int dd = g2 * 8 + hi * 4;
        ushort4 w0, w1;
        w0.x = f2b(O0[4 * g2 + 0] * inv); w0.y = f2b(O0[4 * g2 + 1] * inv);
        w0.z = f2b(O0[4 * g2 + 2] * inv); w0.w = f2b(O0[4 * g2 + 3] * inv);
        w1.x = f2b(O1[4 * g2 + 0] * inv); w1.y = f2b(O1[4 * g2 + 1] * inv);
        w1.z = f2b(O1[4 * g2 + 2] * inv); w1.w = f2b(O1[4 * g2 + 3] * inv);
        *(ushort4*)(ab + dd)      = w0;
        *(ushort4*)(ab + 32 + dd) = w1;
    }
}

// ---------------------------------------------------------------------------
extern "C" void kernel_launch(void* const* d_in, const int* in_sizes, int n_in,
                              void* d_out, int out_size, void* d_ws, size_t ws_size,
                              hipStream_t stream)
{
    const float* x    = (const float*)d_in[0];
    const float* Wqkv = (const float*)d_in[1];
    const float* Wout = (const float*)d_in[2];
    const float* bout = (const float*)d_in[3];
    float* out = (float*)d_out;

    char* w = (char*)d_ws;
    u16* qkvb    = (u16*)(w);                   // 25,165,824  (dead after prep)
    u16* xb      = (u16*)(w + 25165824);        //  8,388,608  (dead after gemm1)
    u16* WqkvT   = (u16*)(w + 33554432);        //  6,291,456  (dead after gemm1)
    u16* WoutT   = (u16*)(w + 39845888);        //  2,097,152
    u16* aob     = (u16*)(w + 41943040);        //  8,388,608
    u16* Qb      = (u16*)(w + 50331648);        //  8,388,608
    u16* Kb      = (u16*)(w + 58720256);        //  8,388,608
    u16* Vimg    = (u16*)(w + 67108864);        //  8,388,608
    float* ctab  = (float*)(w + 75497472);      //    524,288
    float* stab  = (float*)(w + 76021760);      //    524,288

    dim3 blk(256);
    setup_kernel<<<dim3(8704), blk, 0, stream>>>(x, Wqkv, Wout, xb, WqkvT, WoutT, ctab, stab);
    gemm_bt_mfma<1><<<dim3(24, 32), blk, 0, stream>>>(xb, WqkvT, qkvb, nullptr, 4096, 3072, 1024);
    prep_kernel<<<dim3(32, 32), blk, 0, stream>>>(qkvb, ctab, stab, Qb, Kb, Vimg);
    attn32_kernel<<<dim3(512), blk, 0, stream>>>(Qb, Kb, Vimg, aob);
    gemm_bt_mfma<0><<<dim3(8, 32), blk, 0, stream>>>(aob, WoutT, out, bout, 4096, 1024, 1024);
}

// Round 13
// 189.146 us; speedup vs baseline: 1.1204x; 1.0038x over previous
//
#include <hip/hip_runtime.h>
#include <math.h>

// B=2, T=2048, DIM=1024, H=16, HD=64. Inputs fp32, output fp32.
// R11-R18: attn rebuilt (Vimg, VALU L-row, counted-vmcnt 3-parity pipeline,
// XCD swizzle, K=16 PV via permlane32_swap, no K-split, direct bf16 out).
// R19/R20: GEMM got the counted-vmcnt pipeline + LDS-bounce bf16 epilogue
// (total 199 -> 190us; gemm1 out of top-5; attn WRITE 33->8MB).
// R24: attn is #1 again (48.5us). Counters: MFMA 259 cyc/wave-round (exact
// minimal count), VALU 352, wall 1819/SIMD-round at 2 free-running waves ->
// 67% busy, ~600 cyc/round fixed overhead (vmcnt+barrier+ds_read latency+
// MFMA->EXP2 dependency) paid 64x. Fix: 64-key rounds (2 tiles/round, 32
// rounds) halve the overhead count; LDS 48KB (3 parities x 2 tiles), still
// 2 blocks/CU. Compute ordered QK0,QK1 (issue covers latency), exp0/pack0,
// PV0, exp1/pack1 (VALU overlaps PV0 drain), PV1.

typedef unsigned short u16;
typedef __attribute__((ext_vector_type(8))) short short8;
typedef __attribute__((ext_vector_type(4))) short short4v;
typedef __attribute__((ext_vector_type(4))) float f32x4;
typedef __attribute__((ext_vector_type(16))) float f32x16;

#define T_SEQ 2048

#if __has_builtin(__builtin_amdgcn_exp2f)
#define EXP2(x) __builtin_amdgcn_exp2f(x)
#else
#define EXP2(x) exp2f(x)
#endif

__device__ __forceinline__ float b2f(u16 u) {
    union { unsigned int i; float f; } x; x.i = ((unsigned int)u) << 16; return x.f;
}
__device__ __forceinline__ u16 f2b(float f) {
    union { float f; unsigned int i; } x; x.f = f;
    return (u16)((x.i + 0x7FFFu + ((x.i >> 16) & 1u)) >> 16);  // RNE
}
__device__ __forceinline__ void gl_lds16(const u16* g, u16* l) {
    __builtin_amdgcn_global_load_lds(
        (const __attribute__((address_space(1))) unsigned int*)g,
        (__attribute__((address_space(3))) unsigned int*)l, 16, 0, 0);
}
// pack 2 fp32 -> 1 u32 of 2 bf16 (truncation; tiny bias, verified absmax ok)
__device__ __forceinline__ unsigned int packpair(float a, float b) {
    union { float f; unsigned int u; } xa, xb; xa.f = a; xb.f = b;
    return (xa.u >> 16) | (xb.u & 0xffff0000u);
}

// ---------------------------------------------------------------------------
// Fused setup: [0,4096) cast x->bf16; [4096,7168) transpose Wqkv;
// [7168,8192) transpose Wout; [8192,8704) rope table.
// ---------------------------------------------------------------------------
__global__ __launch_bounds__(256) void setup_kernel(
    const float* __restrict__ x, const float* __restrict__ Wqkv,
    const float* __restrict__ Wout, u16* __restrict__ xb,
    u16* __restrict__ WqkvT, u16* __restrict__ WoutT,
    float* __restrict__ costab, float* __restrict__ sintab)
{
    const int bid = blockIdx.x;
    const int tid = threadIdx.x;

    if (bid < 4096) {
        int i = (bid * 256 + tid) * 4;
        float4 v = *(const float4*)(x + i);
        ushort4 w;
        w.x = f2b(v.x); w.y = f2b(v.y); w.z = f2b(v.z); w.w = f2b(v.w);
        *(ushort4*)(xb + i) = w;
        return;
    }
    if (bid < 8192) {
        const float* in; u16* out; int R, Cn, bx, by;
        if (bid < 7168) { in = Wqkv; out = WqkvT; R = 1024; Cn = 3072;
                          int id = bid - 4096; bx = id % 96; by = id / 96; }
        else            { in = Wout; out = WoutT; R = 1024; Cn = 1024;
                          int id = bid - 7168; bx = id & 31; by = id >> 5; }
        __shared__ u16 tile[32][33];
        const int tx = tid & 31, ty = tid >> 5;
        const int r0 = by * 32, c0 = bx * 32;
#pragma unroll
        for (int rr = ty; rr < 32; rr += 8)
            tile[tx][rr] = f2b(in[(size_t)(r0 + rr) * Cn + c0 + tx]);
        __syncthreads();
#pragma unroll
        for (int rr = ty; rr < 32; rr += 8)
            out[(size_t)(c0 + rr) * R + r0 + tx] = tile[rr][tx];
        return;
    }
    {
        int idx = (bid - 8192) * 256 + tid;
        int t = idx >> 6, d = idx & 63;
        const float nl32 = -0.28782313662425576f;   // -ln(10000)/32
        float f = __expf((float)(d & 31) * nl32);
        float s, c;
        __sincosf((float)t * f, &s, &c);
        costab[idx] = c; sintab[idx] = s;
    }
}

// ---------------------------------------------------------------------------
// MFMA GEMM, counted-vmcnt 3-parity pipeline (R19): C[M,N] = A @ Bt^T (+bias).
// OBF=1: bf16 out via LDS-bounce coalesced epilogue. OBF=0: fp32 out direct.
// ---------------------------------------------------------------------------
template<int OBF>
__global__ __launch_bounds__(256) void gemm_bt_mfma(
    const u16* __restrict__ A, const u16* __restrict__ Bt,
    void* __restrict__ Cv, const float* __restrict__ bias,
    int M, int N, int K)
{
    __shared__ u16 sbuf[24576];   // 48 KB: As parities [0,12288), Bs [12288,24576)
    u16* const As0 = sbuf;
    u16* const Bs0 = sbuf + 12288;

    const int tid = threadIdx.x;
    const int wave = tid >> 6, lane = tid & 63;
    const int col = lane & 15, quad = lane >> 4;
    const int wm = (wave & 1) * 64, wn = (wave >> 1) * 64;
    const int m0 = blockIdx.y * 128, n0 = blockIdx.x * 128;

    f32x4 acc[4][4];
#pragma unroll
    for (int i = 0; i < 4; ++i)
#pragma unroll
        for (int j = 0; j < 4; ++j) acc[i][j] = f32x4{0.f, 0.f, 0.f, 0.f};

    const int c1 = tid, c2 = tid + 256;
    const u16* a1 = A + (size_t)(m0 + (c1 >> 2)) * K + (c1 & 3) * 8;
    const u16* a2 = A + (size_t)(m0 + (c2 >> 2)) * K + (c2 & 3) * 8;
    const u16* b1 = Bt + (size_t)(n0 + (c1 >> 2)) * K + (c1 & 3) * 8;
    const u16* b2 = Bt + (size_t)(n0 + (c2 >> 2)) * K + (c2 & 3) * 8;
    const int l1 = c1 * 8, l2 = c2 * 8;

#define GST(p, ks) do { const int k0_ = (ks) * 32;                            \
        gl_lds16(a1 + k0_, As0 + (p) * 4096 + l1);                            \
        gl_lds16(a2 + k0_, As0 + (p) * 4096 + l2);                            \
        gl_lds16(b1 + k0_, Bs0 + (p) * 4096 + l1);                            \
        gl_lds16(b2 + k0_, Bs0 + (p) * 4096 + l2);                            \
    } while (0)

    const int NK = K >> 5;
    // prologue: k-steps 0,1 in flight (8 DMAs/wave)
    GST(0, 0);
    GST(1, 1);

    int cur = 0, prv = 2;
    for (int ks = 0; ks < NK; ++ks) {
        // own k-step's 4 DMAs landed (oldest); next step's 4 stay in flight
        if (ks < NK - 1) asm volatile("s_waitcnt vmcnt(4)" ::: "memory");
        else             asm volatile("s_waitcnt vmcnt(0)" ::: "memory");
        __builtin_amdgcn_s_barrier();
        asm volatile("" ::: "memory");          // compiler fence
        __builtin_amdgcn_sched_barrier(0);      // rule #18: pin MIR scheduler

        // (1) read-first: pull fragments from parity cur
        short8 af[4], bfr[4];
        const u16* Ap = As0 + cur * 4096;
        const u16* Bp = Bs0 + cur * 4096;
#pragma unroll
        for (int i = 0; i < 4; ++i) {
            af[i]  = *(const short8*)&Ap[(wm + i * 16 + col) * 32 + quad * 8];
            bfr[i] = *(const short8*)&Bp[(wn + i * 16 + col) * 32 + quad * 8];
        }

        // (2) stage k-step ks+2 into parity prv (freed by this barrier)
        if (ks < NK - 2) GST(prv, ks + 2);

        // (3) register-only MFMA
        __builtin_amdgcn_s_setprio(1);
#pragma unroll
        for (int i = 0; i < 4; ++i)
#pragma unroll
            for (int j = 0; j < 4; ++j)
                acc[i][j] = __builtin_amdgcn_mfma_f32_16x16x32_bf16(
                    af[i], bfr[j], acc[i][j], 0, 0, 0);
        __builtin_amdgcn_s_setprio(0);

        prv = cur;
        cur = (cur == 2) ? 0 : cur + 1;
    }
#undef GST

    if (OBF) {
        // bf16 out: bounce through LDS ([128][136] u16; stride 272B = 17*16
        // keeps b128 accesses aligned and breaks power-of-2 bank aliasing),
        // then 128B contiguous per thread -> full-line HBM writes, no RMW.
        __syncthreads();
        u16* Cs = sbuf;   // 128*136*2 = 34816 B of the 48 KB
#pragma unroll
        for (int j = 0; j < 4; ++j) {
            const int cl = wn + j * 16 + col;
            const float bv = bias ? bias[n0 + cl] : 0.f;
#pragma unroll
            for (int i = 0; i < 4; ++i) {
                const int rl = wm + i * 16 + quad * 4;
#pragma unroll
                for (int r = 0; r < 4; ++r)
                    Cs[(rl + r) * 136 + cl] = f2b(acc[i][j][r] + bv);
            }
        }
        __syncthreads();
        // thread t owns row = t>>1, half = t&1: 64 contiguous u16 (128B)
        const int row = tid >> 1, half = tid & 1;
        const u16* src = Cs + row * 136 + half * 64;
        u16* dst = (u16*)Cv + (size_t)(m0 + row) * N + n0 + half * 64;
#pragma unroll
        for (int s = 0; s < 8; ++s)
            *(short8*)(dst + s * 8) = *(const short8*)(src + s * 8);
    } else {
        // fp32 out: direct stores (64B per 16 lanes, line-friendly) + bias
#pragma unroll
        for (int j = 0; j < 4; ++j) {
            int n = n0 + wn + j * 16 + col;
            float bv = bias ? bias[n] : 0.f;
#pragma unroll
            for (int i = 0; i < 4; ++i) {
                int mbase = m0 + wm + i * 16 + quad * 4;
#pragma unroll
                for (int r = 0; r < 4; ++r)
                    ((float*)Cv)[(size_t)(mbase + r) * N + n] = acc[i][j][r] + bv;
            }
        }
    }
}

// ---------------------------------------------------------------------------
// Prep: qkvb bf16 -> rope(q)*0.125*log2e, rope(k) head-major Qb/Kb[bh][t][64];
// V written as attn LDS-image for 32x32x16 A-frags (R17 layout).
// ---------------------------------------------------------------------------
__global__ __launch_bounds__(256) void prep_kernel(
    const u16* __restrict__ qkvb, const float* __restrict__ costab,
    const float* __restrict__ sintab, u16* __restrict__ Qb,
    u16* __restrict__ Kb, u16* __restrict__ Vimg)
{
    __shared__ u16 Vls[64][72];

    const int tid = threadIdx.x;
    const int bh = blockIdx.y;
    const int t0 = blockIdx.x * 64;
    const int b = bh >> 4, h = bh & 15;
    const int t_loc = tid >> 2;
    const int d0 = (tid & 3) * 16;

    const int t = t0 + t_loc;
    const u16* qp = qkvb + ((size_t)(b * T_SEQ + t)) * 3072 + h * 64 + d0;

    float ct[16], st[16];
    {
        const float* cp = costab + (size_t)t * 64 + d0;
        const float* sp = sintab + (size_t)t * 64 + d0;
#pragma unroll
        for (int j = 0; j < 16; j += 4) {
            *(float4*)&ct[j] = *(const float4*)(cp + j);
            *(float4*)&st[j] = *(const float4*)(sp + j);
        }
    }

#pragma unroll
    for (int part = 0; part < 2; ++part) {
        // fold QK^T scale AND log2(e) into Q: p = 2^(s_scaled) in attn.
        const float sc = part ? 1.f : 0.18033688011112042f;  // 0.125*log2(e)
        const u16* src = qp + part * 1024;
        u16* dst = (part ? Kb : Qb) + ((size_t)(bh * T_SEQ + t)) * 64 + d0;
        short8 v0 = *(const short8*)(src);
        short8 v1 = *(const short8*)(src + 8);
        float f[16];
#pragma unroll
        for (int j = 0; j < 8; ++j) { f[j] = b2f((u16)v0[j]); f[8 + j] = b2f((u16)v1[j]); }
        u16 o[16];
#pragma unroll
        for (int i = 0; i < 8; ++i) {
            float e = f[2 * i], od = f[2 * i + 1];
            o[2 * i]     = f2b((e * ct[2 * i]      - od * st[2 * i]) * sc);
            o[2 * i + 1] = f2b((od * ct[2 * i + 1] + e  * st[2 * i + 1]) * sc);
        }
        *(short8*)(dst)     = *(short8*)&o[0];
        *(short8*)(dst + 8) = *(short8*)&o[8];
    }

    {
        const u16* src = qp + 2048;
        *(short8*)&Vls[t_loc][d0]     = *(const short8*)(src);
        *(short8*)&Vls[t_loc][d0 + 8] = *(const short8*)(src + 8);
    }
    __syncthreads();
    {
        // R17 region layout: region = tid>>6 = m_*2+db; m_ = key-half,
        // db = dim-half; h2 = A-frag hi, dv = dim-within-32.
        const int m_  = (tid >> 7) & 1;
        const int db  = (tid >> 6) & 1;
        const int h2  = (tid >> 5) & 1;
        const int dv  = tid & 31;
        const int k0v = m_ * 16 + h2 * 8;
        const int dcol = db * 32 + dv;
        const int kt_base = blockIdx.x * 2;   // two 32-key tiles per block
#pragma unroll
        for (int ktl = 0; ktl < 2; ++ktl) {
            u16 o[8];
#pragma unroll
            for (int j = 0; j < 8; ++j)
                o[j] = Vls[ktl * 32 + k0v + j][dcol];
            u16* dst = Vimg + ((size_t)(bh * 64 + kt_base + ktl)) * 2048 + tid * 8;
            *(short8*)dst = *(short8*)&o[0];
        }
    }
}

// ---------------------------------------------------------------------------
// MFMA flash attention, R24: counted-vmcnt 3-parity pipeline with 64-key
// rounds (2 tiles/round, 32 rounds) to halve per-round overhead. Wave = 32
// q-rows; block = 4 waves; grid 512 XCD-swizzled; K=16 PV via
// permlane32_swap; direct bf16 epilogue into head-merged aob.
// ---------------------------------------------------------------------------
__global__ __launch_bounds__(256, 2) void attn32_kernel(
    const u16* __restrict__ Qb, const u16* __restrict__ Kb,
    const u16* __restrict__ Vimg, u16* __restrict__ aob)
{
    __shared__ u16 Kbuf[3][2][2048];   // [parity][half][tile]  24 KB
    __shared__ u16 Vbuf[3][2][2048];   // 24 KB

    const int tid = threadIdx.x;
    const int wave = tid >> 6, lane = tid & 63;
    const int qcol = lane & 31;
    const int hi = lane >> 5;

    const int bid = blockIdx.x;
    const int lbid = (bid & 7) * 64 + (bid >> 3);
    const int bh = lbid >> 4;
    const int qblk = lbid & 15;
    const int qrow0 = qblk * 128 + wave * 32;

    // Q B-frags (32x32x16): lane(n=q, hi): Q[q][c*16 + hi*8 + j]
    short8 qa[4];
    {
        const u16* qp = Qb + ((size_t)(bh * T_SEQ + qrow0 + qcol)) * 64 + hi * 8;
#pragma unroll
        for (int c = 0; c < 4; ++c) qa[c] = *(const short8*)(qp + c * 16);
    }

    f32x16 O0, O1;
#pragma unroll
    for (int i = 0; i < 16; ++i) { O0[i] = 0.f; O1[i] = 0.f; }
    float Lacc = 0.f;

    const u16* kg_ptr = Kb + ((size_t)bh * T_SEQ + qcol) * 64 + wave * 16 + hi * 8;
    const u16* vg_ptr = Vimg + ((size_t)bh * 64) * 2048 + tid * 8;

#define STAGE2(p, rr) do {                                                    \
        gl_lds16(kg_ptr + (size_t)(2 * (rr))     * 2048, &Kbuf[p][0][tid * 8]);\
        gl_lds16(kg_ptr + (size_t)(2 * (rr) + 1) * 2048, &Kbuf[p][1][tid * 8]);\
        gl_lds16(vg_ptr + (size_t)(2 * (rr))     * 2048, &Vbuf[p][0][tid * 8]);\
        gl_lds16(vg_ptr + (size_t)(2 * (rr) + 1) * 2048, &Vbuf[p][1][tid * 8]);\
    } while (0)

    // prologue: rounds 0,1 in flight (8 DMAs/wave)
    STAGE2(0, 0);
    STAGE2(1, 1);

    int cur = 0, prv = 2;
    for (int r = 0; r < 32; ++r) {
        // own round's 4 DMAs landed (oldest); next round's 4 stay in flight
        if (r < 31) asm volatile("s_waitcnt vmcnt(4)" ::: "memory");
        else        asm volatile("s_waitcnt vmcnt(0)" ::: "memory");
        __builtin_amdgcn_s_barrier();
        asm volatile("" ::: "memory");          // compiler fence
        __builtin_amdgcn_sched_barrier(0);      // rule #18

        // (1) read-first: both halves' K/V fragments into registers
        short8 kf[2][4], vA[2][4];
#pragma unroll
        for (int half = 0; half < 2; ++half) {
#pragma unroll
            for (int f = 0; f < 4; ++f)
                kf[half][f] = *(const short8*)&Kbuf[cur][half][(f * 64 + lane) * 8];
#pragma unroll
            for (int rg = 0; rg < 4; ++rg)
                vA[half][rg] = *(const short8*)&Vbuf[cur][half][rg * 512 + lane * 8];
        }

        // (2) stage round r+2 into parity prv (freed by this barrier)
        if (r < 30) STAGE2(prv, r + 2);

        // (3) QK both halves back-to-back: QK1's issue covers QK0's latency
        f32x16 sT0, sT1;
#pragma unroll
        for (int ii = 0; ii < 16; ++ii) { sT0[ii] = 0.f; sT1[ii] = 0.f; }
        __builtin_amdgcn_s_setprio(1);
#pragma unroll
        for (int c = 0; c < 4; ++c)
            sT0 = __builtin_amdgcn_mfma_f32_32x32x16_bf16(kf[0][c], qa[c], sT0, 0, 0, 0);
#pragma unroll
        for (int c = 0; c < 4; ++c)
            sT1 = __builtin_amdgcn_mfma_f32_32x32x16_bf16(kf[1][c], qa[c], sT1, 0, 0, 0);
        __builtin_amdgcn_s_setprio(0);

        // half 0: exp/pack (VALU) then PV (MFMA)
        {
            float pe[16];
#pragma unroll
            for (int ii = 0; ii < 16; ++ii) pe[ii] = EXP2(sT0[ii]);
#pragma unroll
            for (int g = 0; g < 4; ++g)
                Lacc += (pe[4 * g + 0] + pe[4 * g + 1]) +
                        (pe[4 * g + 2] + pe[4 * g + 3]);
            unsigned int W0 = packpair(pe[0],  pe[1]);
            unsigned int W1 = packpair(pe[2],  pe[3]);
            unsigned int W2 = packpair(pe[4],  pe[5]);
            unsigned int W3 = packpair(pe[6],  pe[7]);
            unsigned int W4 = packpair(pe[8],  pe[9]);
            unsigned int W5 = packpair(pe[10], pe[11]);
            unsigned int W6 = packpair(pe[12], pe[13]);
            unsigned int W7 = packpair(pe[14], pe[15]);
            asm volatile("v_permlane32_swap_b32 %0, %1" : "+v"(W0), "+v"(W2));
            asm volatile("v_permlane32_swap_b32 %0, %1" : "+v"(W1), "+v"(W3));
            asm volatile("v_permlane32_swap_b32 %0, %1" : "+v"(W4), "+v"(W6));
            asm volatile("v_permlane32_swap_b32 %0, %1" : "+v"(W5), "+v"(W7));
            union FU { unsigned int u[4]; short8 s; } f0, f1;
            f0.u[0] = W0; f0.u[1] = W1; f0.u[2] = W2; f0.u[3] = W3;
            f1.u[0] = W4; f1.u[1] = W5; f1.u[2] = W6; f1.u[3] = W7;
            __builtin_amdgcn_s_setprio(1);
            O0 = __builtin_amdgcn_mfma_f32_32x32x16_bf16(vA[0][0], f0.s, O0, 0, 0, 0);
            O1 = __builtin_amdgcn_mfma_f32_32x32x16_bf16(vA[0][1], f0.s, O1, 0, 0, 0);
            O0 = __builtin_amdgcn_mfma_f32_32x32x16_bf16(vA[0][2], f1.s, O0, 0, 0, 0);
            O1 = __builtin_amdgcn_mfma_f32_32x32x16_bf16(vA[0][3], f1.s, O1, 0, 0, 0);
            __builtin_amdgcn_s_setprio(0);
        }
        // half 1: exp/pack issues while PV0 drains (separate pipes)
        {
            float pe[16];
#pragma unroll
            for (int ii = 0; ii < 16; ++ii) pe[ii] = EXP2(sT1[ii]);
#pragma unroll
            for (int g = 0; g < 4; ++g)
                Lacc += (pe[4 * g + 0] + pe[4 * g + 1]) +
                        (pe[4 * g + 2] + pe[4 * g + 3]);
            unsigned int W0 = packpair(pe[0],  pe[1]);
            unsigned int W1 = packpair(pe[2],  pe[3]);
            unsigned int W2 = packpair(pe[4],  pe[5]);
            unsigned int W3 = packpair(pe[6],  pe[7]);
            unsigned int W4 = packpair(pe[8],  pe[9]);
            unsigned int W5 = packpair(pe[10], pe[11]);
            unsigned int W6 = packpair(pe[12], pe[13]);
            unsigned int W7 = packpair(pe[14], pe[15]);
            asm volatile("v_permlane32_swap_b32 %0, %1" : "+v"(W0), "+v"(W2));
            asm volatile("v_permlane32_swap_b32 %0, %1" : "+v"(W1), "+v"(W3));
            asm volatile("v_permlane32_swap_b32 %0, %1" : "+v"(W4), "+v"(W6));
            asm volatile("v_permlane32_swap_b32 %0, %1" : "+v"(W5), "+v"(W7));
            union FU { unsigned int u[4]; short8 s; } f0, f1;
            f0.u[0] = W0; f0.u[1] = W1; f0.u[2] = W2; f0.u[3] = W3;
            f1.u[0] = W4; f1.u[1] = W5; f1.u[2] = W6; f1.u[3] = W7;
            __builtin_amdgcn_s_setprio(1);
            O0 = __builtin_amdgcn_mfma_f32_32x32x16_bf16(vA[1][0], f0.s, O0, 0, 0, 0);
            O1 = __builtin_amdgcn_mfma_f32_32x32x16_bf16(vA[1][1], f0.s, O1, 0, 0, 0);
            O0 = __builtin_amdgcn_mfma_f32_32x32x16_bf16(vA[1][2], f1.s, O0, 0, 0, 0);
            O1 = __builtin_amdgcn_mfma_f32_32x32x16_bf16(vA[1][3], f1.s, O1, 0, 0, 0);
            __builtin_amdgcn_s_setprio(0);
        }

        prv = cur;
        cur = (cur == 2) ? 0 : cur + 1;
    }
#undef STAGE2

    float Lq = Lacc + __shfl(Lacc, lane ^ 32);
    float inv = 1.f / Lq;

    const int b = bh >> 4, h = bh & 15;
    u16* ab = aob + ((size_t)(b * T_SEQ + qrow0 + qcol)) * 1024 + h * 64;
#pragma unroll
    for (int g2 = 0; g2 < 4; ++g2) {
        int dd = g2 * 8 + hi * 4;
        ushort4 w0, w1;
        w0.x = f2b(O0[4 * g2 + 0] * inv); w0.y = f2b(O0[4 * g2 + 1] * inv);
        w0.z = f2b(O0[4 * g2 + 2] * inv); w0.w = f2b(O0[4 * g2 + 3] * inv);
        w1.x = f2b(O1[4 * g2 + 0] * inv); w1.y = f2b(O1[4 * g2 + 1] * inv);
        w1.z = f2b(O1[4 * g2 + 2] * inv); w1.w = f2b(O1[4 * g2 + 3] * inv);
        *(ushort4*)(ab + dd)      = w0;
        *(ushort4*)(ab + 32 + dd) = w1;
    }
}

// ---------------------------------------------------------------------------
extern "C" void kernel_launch(void* const* d_in, const int* in_sizes, int n_in,
                              void* d_out, int out_size, void* d_ws, size_t ws_size,
                              hipStream_t stream)
{
    const float* x    = (const float*)d_in[0];
    const float* Wqkv = (const float*)d_in[1];
    const float* Wout = (const float*)d_in[2];
    const float* bout = (const float*)d_in[3];
    float* out = (float*)d_out;

    char* w = (char*)d_ws;
    u16* qkvb    = (u16*)(w);                   // 25,165,824  (dead after prep)
    u16* xb      = (u16*)(w + 25165824);        //  8,388,608  (dead after gemm1)
    u16* WqkvT   = (u16*)(w + 33554432);        //  6,291,456  (dead after gemm1)
    u16* WoutT   = (u16*)(w + 39845888);        //  2,097,152
    u16* aob     = (u16*)(w + 41943040);        //  8,388,608
    u16* Qb      = (u16*)(w + 50331648);        //  8,388,608
    u16* Kb      = (u16*)(w + 58720256);        //  8,388,608
    u16* Vimg    = (u16*)(w + 67108864);        //  8,388,608
    float* ctab  = (float*)(w + 75497472);      //    524,288
    float* stab  = (float*)(w + 76021760);      //    524,288

    dim3 blk(256);
    setup_kernel<<<dim3(8704), blk, 0, stream>>>(x, Wqkv, Wout, xb, WqkvT, WoutT, ctab, stab);
    gemm_bt_mfma<1><<<dim3(24, 32), blk, 0, stream>>>(xb, WqkvT, qkvb, nullptr, 4096, 3072, 1024);
    prep_kernel<<<dim3(32, 32), blk, 0, stream>>>(qkvb, ctab, stab, Qb, Kb, Vimg);
    attn32_kernel<<<dim3(512), blk, 0, stream>>>(Qb, Kb, Vimg, aob);
    gemm_bt_mfma<0><<<dim3(8, 32), blk, 0, stream>>>(aob, WoutT, out, bout, 4096, 1024, 1024);
}

// Round 14
// 186.193 us; speedup vs baseline: 1.1382x; 1.0159x over previous
//
#include <hip/hip_runtime.h>
#include <math.h>

// B=2, T=2048, DIM=1024, H=16, HD=64. Inputs fp32, output fp32.
// R11-R20: attn rebuilt (Vimg, VALU L-row, counted-vmcnt 3-parity pipeline,
// XCD swizzle, K=16 PV, direct bf16 out); GEMM pipelined + LDS-bounce
// epilogue. 223 -> 189us.
// R24: 64-key rounds = flat (48.5 -> 48.3) => per-round overhead NOT the
// binding term. Measured 32 cyc/MFMA vs 8-cyc ubench throughput: the stall
// is dependent-accumulate chain latency (QK: serial 4-chain into sT; PV:
// all 8 mfma into the same O0/O1 = 2 chains of 4). Waves scoreboard-stall
// between their own MFMAs; 2 waves/SIMD can't fill the gaps.
// R25: break the chains. (a) interleave sT0/sT1 QK mfmas (2-way);
// (b) PV half0 -> O0a/O1a, half1 -> O0b/O1b (4 independent chains; half1
// issues don't wait on half0), sum at epilogue (+32 VGPR). exp/pack(half1)
// VALU now truly overlaps PV0 execution.

typedef unsigned short u16;
typedef __attribute__((ext_vector_type(8))) short short8;
typedef __attribute__((ext_vector_type(4))) short short4v;
typedef __attribute__((ext_vector_type(4))) float f32x4;
typedef __attribute__((ext_vector_type(16))) float f32x16;

#define T_SEQ 2048

#if __has_builtin(__builtin_amdgcn_exp2f)
#define EXP2(x) __builtin_amdgcn_exp2f(x)
#else
#define EXP2(x) exp2f(x)
#endif

__device__ __forceinline__ float b2f(u16 u) {
    union { unsigned int i; float f; } x; x.i = ((unsigned int)u) << 16; return x.f;
}
__device__ __forceinline__ u16 f2b(float f) {
    union { float f; unsigned int i; } x; x.f = f;
    return (u16)((x.i + 0x7FFFu + ((x.i >> 16) & 1u)) >> 16);  // RNE
}
__device__ __forceinline__ void gl_lds16(const u16* g, u16* l) {
    __builtin_amdgcn_global_load_lds(
        (const __attribute__((address_space(1))) unsigned int*)g,
        (__attribute__((address_space(3))) unsigned int*)l, 16, 0, 0);
}
// pack 2 fp32 -> 1 u32 of 2 bf16 (truncation; tiny bias, verified absmax ok)
__device__ __forceinline__ unsigned int packpair(float a, float b) {
    union { float f; unsigned int u; } xa, xb; xa.f = a; xb.f = b;
    return (xa.u >> 16) | (xb.u & 0xffff0000u);
}

// ---------------------------------------------------------------------------
// Fused setup: [0,4096) cast x->bf16; [4096,7168) transpose Wqkv;
// [7168,8192) transpose Wout; [8192,8704) rope table.
// ---------------------------------------------------------------------------
__global__ __launch_bounds__(256) void setup_kernel(
    const float* __restrict__ x, const float* __restrict__ Wqkv,
    const float* __restrict__ Wout, u16* __restrict__ xb,
    u16* __restrict__ WqkvT, u16* __restrict__ WoutT,
    float* __restrict__ costab, float* __restrict__ sintab)
{
    const int bid = blockIdx.x;
    const int tid = threadIdx.x;

    if (bid < 4096) {
        int i = (bid * 256 + tid) * 4;
        float4 v = *(const float4*)(x + i);
        ushort4 w;
        w.x = f2b(v.x); w.y = f2b(v.y); w.z = f2b(v.z); w.w = f2b(v.w);
        *(ushort4*)(xb + i) = w;
        return;
    }
    if (bid < 8192) {
        const float* in; u16* out; int R, Cn, bx, by;
        if (bid < 7168) { in = Wqkv; out = WqkvT; R = 1024; Cn = 3072;
                          int id = bid - 4096; bx = id % 96; by = id / 96; }
        else            { in = Wout; out = WoutT; R = 1024; Cn = 1024;
                          int id = bid - 7168; bx = id & 31; by = id >> 5; }
        __shared__ u16 tile[32][33];
        const int tx = tid & 31, ty = tid >> 5;
        const int r0 = by * 32, c0 = bx * 32;
#pragma unroll
        for (int rr = ty; rr < 32; rr += 8)
            tile[tx][rr] = f2b(in[(size_t)(r0 + rr) * Cn + c0 + tx]);
        __syncthreads();
#pragma unroll
        for (int rr = ty; rr < 32; rr += 8)
            out[(size_t)(c0 + rr) * R + r0 + tx] = tile[rr][tx];
        return;
    }
    {
        int idx = (bid - 8192) * 256 + tid;
        int t = idx >> 6, d = idx & 63;
        const float nl32 = -0.28782313662425576f;   // -ln(10000)/32
        float f = __expf((float)(d & 31) * nl32);
        float s, c;
        __sincosf((float)t * f, &s, &c);
        costab[idx] = c; sintab[idx] = s;
    }
}

// ---------------------------------------------------------------------------
// MFMA GEMM, counted-vmcnt 3-parity pipeline (R19): C[M,N] = A @ Bt^T (+bias).
// OBF=1: bf16 out via LDS-bounce coalesced epilogue. OBF=0: fp32 out direct.
// ---------------------------------------------------------------------------
template<int OBF>
__global__ __launch_bounds__(256) void gemm_bt_mfma(
    const u16* __restrict__ A, const u16* __restrict__ Bt,
    void* __restrict__ Cv, const float* __restrict__ bias,
    int M, int N, int K)
{
    __shared__ u16 sbuf[24576];   // 48 KB: As parities [0,12288), Bs [12288,24576)
    u16* const As0 = sbuf;
    u16* const Bs0 = sbuf + 12288;

    const int tid = threadIdx.x;
    const int wave = tid >> 6, lane = tid & 63;
    const int col = lane & 15, quad = lane >> 4;
    const int wm = (wave & 1) * 64, wn = (wave >> 1) * 64;
    const int m0 = blockIdx.y * 128, n0 = blockIdx.x * 128;

    f32x4 acc[4][4];
#pragma unroll
    for (int i = 0; i < 4; ++i)
#pragma unroll
        for (int j = 0; j < 4; ++j) acc[i][j] = f32x4{0.f, 0.f, 0.f, 0.f};

    const int c1 = tid, c2 = tid + 256;
    const u16* a1 = A + (size_t)(m0 + (c1 >> 2)) * K + (c1 & 3) * 8;
    const u16* a2 = A + (size_t)(m0 + (c2 >> 2)) * K + (c2 & 3) * 8;
    const u16* b1 = Bt + (size_t)(n0 + (c1 >> 2)) * K + (c1 & 3) * 8;
    const u16* b2 = Bt + (size_t)(n0 + (c2 >> 2)) * K + (c2 & 3) * 8;
    const int l1 = c1 * 8, l2 = c2 * 8;

#define GST(p, ks) do { const int k0_ = (ks) * 32;                            \
        gl_lds16(a1 + k0_, As0 + (p) * 4096 + l1);                            \
        gl_lds16(a2 + k0_, As0 + (p) * 4096 + l2);                            \
        gl_lds16(b1 + k0_, Bs0 + (p) * 4096 + l1);                            \
        gl_lds16(b2 + k0_, Bs0 + (p) * 4096 + l2);                            \
    } while (0)

    const int NK = K >> 5;
    // prologue: k-steps 0,1 in flight (8 DMAs/wave)
    GST(0, 0);
    GST(1, 1);

    int cur = 0, prv = 2;
    for (int ks = 0; ks < NK; ++ks) {
        // own k-step's 4 DMAs landed (oldest); next step's 4 stay in flight
        if (ks < NK - 1) asm volatile("s_waitcnt vmcnt(4)" ::: "memory");
        else             asm volatile("s_waitcnt vmcnt(0)" ::: "memory");
        __builtin_amdgcn_s_barrier();
        asm volatile("" ::: "memory");          // compiler fence
        __builtin_amdgcn_sched_barrier(0);      // rule #18: pin MIR scheduler

        // (1) read-first: pull fragments from parity cur
        short8 af[4], bfr[4];
        const u16* Ap = As0 + cur * 4096;
        const u16* Bp = Bs0 + cur * 4096;
#pragma unroll
        for (int i = 0; i < 4; ++i) {
            af[i]  = *(const short8*)&Ap[(wm + i * 16 + col) * 32 + quad * 8];
            bfr[i] = *(const short8*)&Bp[(wn + i * 16 + col) * 32 + quad * 8];
        }

        // (2) stage k-step ks+2 into parity prv (freed by this barrier)
        if (ks < NK - 2) GST(prv, ks + 2);

        // (3) register-only MFMA
        __builtin_amdgcn_s_setprio(1);
#pragma unroll
        for (int i = 0; i < 4; ++i)
#pragma unroll
            for (int j = 0; j < 4; ++j)
                acc[i][j] = __builtin_amdgcn_mfma_f32_16x16x32_bf16(
                    af[i], bfr[j], acc[i][j], 0, 0, 0);
        __builtin_amdgcn_s_setprio(0);

        prv = cur;
        cur = (cur == 2) ? 0 : cur + 1;
    }
#undef GST

    if (OBF) {
        // bf16 out: bounce through LDS ([128][136] u16; stride 272B = 17*16
        // keeps b128 accesses aligned and breaks power-of-2 bank aliasing),
        // then 128B contiguous per thread -> full-line HBM writes, no RMW.
        __syncthreads();
        u16* Cs = sbuf;   // 128*136*2 = 34816 B of the 48 KB
#pragma unroll
        for (int j = 0; j < 4; ++j) {
            const int cl = wn + j * 16 + col;
            const float bv = bias ? bias[n0 + cl] : 0.f;
#pragma unroll
            for (int i = 0; i < 4; ++i) {
                const int rl = wm + i * 16 + quad * 4;
#pragma unroll
                for (int r = 0; r < 4; ++r)
                    Cs[(rl + r) * 136 + cl] = f2b(acc[i][j][r] + bv);
            }
        }
        __syncthreads();
        // thread t owns row = t>>1, half = t&1: 64 contiguous u16 (128B)
        const int row = tid >> 1, half = tid & 1;
        const u16* src = Cs + row * 136 + half * 64;
        u16* dst = (u16*)Cv + (size_t)(m0 + row) * N + n0 + half * 64;
#pragma unroll
        for (int s = 0; s < 8; ++s)
            *(short8*)(dst + s * 8) = *(const short8*)(src + s * 8);
    } else {
        // fp32 out: direct stores (64B per 16 lanes, line-friendly) + bias
#pragma unroll
        for (int j = 0; j < 4; ++j) {
            int n = n0 + wn + j * 16 + col;
            float bv = bias ? bias[n] : 0.f;
#pragma unroll
            for (int i = 0; i < 4; ++i) {
                int mbase = m0 + wm + i * 16 + quad * 4;
#pragma unroll
                for (int r = 0; r < 4; ++r)
                    ((float*)Cv)[(size_t)(mbase + r) * N + n] = acc[i][j][r] + bv;
            }
        }
    }
}

// ---------------------------------------------------------------------------
// Prep: qkvb bf16 -> rope(q)*0.125*log2e, rope(k) head-major Qb/Kb[bh][t][64];
// V written as attn LDS-image for 32x32x16 A-frags (R17 layout).
// ---------------------------------------------------------------------------
__global__ __launch_bounds__(256) void prep_kernel(
    const u16* __restrict__ qkvb, const float* __restrict__ costab,
    const float* __restrict__ sintab, u16* __restrict__ Qb,
    u16* __restrict__ Kb, u16* __restrict__ Vimg)
{
    __shared__ u16 Vls[64][72];

    const int tid = threadIdx.x;
    const int bh = blockIdx.y;
    const int t0 = blockIdx.x * 64;
    const int b = bh >> 4, h = bh & 15;
    const int t_loc = tid >> 2;
    const int d0 = (tid & 3) * 16;

    const int t = t0 + t_loc;
    const u16* qp = qkvb + ((size_t)(b * T_SEQ + t)) * 3072 + h * 64 + d0;

    float ct[16], st[16];
    {
        const float* cp = costab + (size_t)t * 64 + d0;
        const float* sp = sintab + (size_t)t * 64 + d0;
#pragma unroll
        for (int j = 0; j < 16; j += 4) {
            *(float4*)&ct[j] = *(const float4*)(cp + j);
            *(float4*)&st[j] = *(const float4*)(sp + j);
        }
    }

#pragma unroll
    for (int part = 0; part < 2; ++part) {
        // fold QK^T scale AND log2(e) into Q: p = 2^(s_scaled) in attn.
        const float sc = part ? 1.f : 0.18033688011112042f;  // 0.125*log2(e)
        const u16* src = qp + part * 1024;
        u16* dst = (part ? Kb : Qb) + ((size_t)(bh * T_SEQ + t)) * 64 + d0;
        short8 v0 = *(const short8*)(src);
        short8 v1 = *(const short8*)(src + 8);
        float f[16];
#pragma unroll
        for (int j = 0; j < 8; ++j) { f[j] = b2f((u16)v0[j]); f[8 + j] = b2f((u16)v1[j]); }
        u16 o[16];
#pragma unroll
        for (int i = 0; i < 8; ++i) {
            float e = f[2 * i], od = f[2 * i + 1];
            o[2 * i]     = f2b((e * ct[2 * i]      - od * st[2 * i]) * sc);
            o[2 * i + 1] = f2b((od * ct[2 * i + 1] + e  * st[2 * i + 1]) * sc);
        }
        *(short8*)(dst)     = *(short8*)&o[0];
        *(short8*)(dst + 8) = *(short8*)&o[8];
    }

    {
        const u16* src = qp + 2048;
        *(short8*)&Vls[t_loc][d0]     = *(const short8*)(src);
        *(short8*)&Vls[t_loc][d0 + 8] = *(const short8*)(src + 8);
    }
    __syncthreads();
    {
        // R17 region layout: region = tid>>6 = m_*2+db; m_ = key-half,
        // db = dim-half; h2 = A-frag hi, dv = dim-within-32.
        const int m_  = (tid >> 7) & 1;
        const int db  = (tid >> 6) & 1;
        const int h2  = (tid >> 5) & 1;
        const int dv  = tid & 31;
        const int k0v = m_ * 16 + h2 * 8;
        const int dcol = db * 32 + dv;
        const int kt_base = blockIdx.x * 2;   // two 32-key tiles per block
#pragma unroll
        for (int ktl = 0; ktl < 2; ++ktl) {
            u16 o[8];
#pragma unroll
            for (int j = 0; j < 8; ++j)
                o[j] = Vls[ktl * 32 + k0v + j][dcol];
            u16* dst = Vimg + ((size_t)(bh * 64 + kt_base + ktl)) * 2048 + tid * 8;
            *(short8*)dst = *(short8*)&o[0];
        }
    }
}

// ---------------------------------------------------------------------------
// MFMA flash attention, R25: counted-vmcnt 3-parity pipeline, 64-key rounds,
// chain-broken MFMA schedule: QK sT0/sT1 interleaved (2-way); PV half0 ->
// O0a/O1a, half1 -> O0b/O1b (4 independent chains), summed at epilogue.
// Wave = 32 q-rows; block = 4 waves; grid 512 XCD-swizzled; bf16 epilogue.
// ---------------------------------------------------------------------------
__global__ __launch_bounds__(256, 2) void attn32_kernel(
    const u16* __restrict__ Qb, const u16* __restrict__ Kb,
    const u16* __restrict__ Vimg, u16* __restrict__ aob)
{
    __shared__ u16 Kbuf[3][2][2048];   // [parity][half][tile]  24 KB
    __shared__ u16 Vbuf[3][2][2048];   // 24 KB

    const int tid = threadIdx.x;
    const int wave = tid >> 6, lane = tid & 63;
    const int qcol = lane & 31;
    const int hi = lane >> 5;

    const int bid = blockIdx.x;
    const int lbid = (bid & 7) * 64 + (bid >> 3);
    const int bh = lbid >> 4;
    const int qblk = lbid & 15;
    const int qrow0 = qblk * 128 + wave * 32;

    // Q B-frags (32x32x16): lane(n=q, hi): Q[q][c*16 + hi*8 + j]
    short8 qa[4];
    {
        const u16* qp = Qb + ((size_t)(bh * T_SEQ + qrow0 + qcol)) * 64 + hi * 8;
#pragma unroll
        for (int c = 0; c < 4; ++c) qa[c] = *(const short8*)(qp + c * 16);
    }

    f32x16 O0a, O1a, O0b, O1b;
#pragma unroll
    for (int i = 0; i < 16; ++i) { O0a[i] = 0.f; O1a[i] = 0.f; O0b[i] = 0.f; O1b[i] = 0.f; }
    float Lacc = 0.f;

    const u16* kg_ptr = Kb + ((size_t)bh * T_SEQ + qcol) * 64 + wave * 16 + hi * 8;
    const u16* vg_ptr = Vimg + ((size_t)bh * 64) * 2048 + tid * 8;

#define STAGE2(p, rr) do {                                                    \
        gl_lds16(kg_ptr + (size_t)(2 * (rr))     * 2048, &Kbuf[p][0][tid * 8]);\
        gl_lds16(kg_ptr + (size_t)(2 * (rr) + 1) * 2048, &Kbuf[p][1][tid * 8]);\
        gl_lds16(vg_ptr + (size_t)(2 * (rr))     * 2048, &Vbuf[p][0][tid * 8]);\
        gl_lds16(vg_ptr + (size_t)(2 * (rr) + 1) * 2048, &Vbuf[p][1][tid * 8]);\
    } while (0)

    // prologue: rounds 0,1 in flight (8 DMAs/wave)
    STAGE2(0, 0);
    STAGE2(1, 1);

    int cur = 0, prv = 2;
    for (int r = 0; r < 32; ++r) {
        // own round's 4 DMAs landed (oldest); next round's 4 stay in flight
        if (r < 31) asm volatile("s_waitcnt vmcnt(4)" ::: "memory");
        else        asm volatile("s_waitcnt vmcnt(0)" ::: "memory");
        __builtin_amdgcn_s_barrier();
        asm volatile("" ::: "memory");          // compiler fence
        __builtin_amdgcn_sched_barrier(0);      // rule #18

        // (1) read-first: both halves' K/V fragments into registers
        short8 kf[2][4], vA[2][4];
#pragma unroll
        for (int half = 0; half < 2; ++half) {
#pragma unroll
            for (int f = 0; f < 4; ++f)
                kf[half][f] = *(const short8*)&Kbuf[cur][half][(f * 64 + lane) * 8];
#pragma unroll
            for (int rg = 0; rg < 4; ++rg)
                vA[half][rg] = *(const short8*)&Vbuf[cur][half][rg * 512 + lane * 8];
        }

        // (2) stage round r+2 into parity prv (freed by this barrier)
        if (r < 30) STAGE2(prv, r + 2);

        // (3) QK: sT0/sT1 INTERLEAVED -> each chain's next link 2 issues away
        f32x16 sT0, sT1;
#pragma unroll
        for (int ii = 0; ii < 16; ++ii) { sT0[ii] = 0.f; sT1[ii] = 0.f; }
        __builtin_amdgcn_s_setprio(1);
#pragma unroll
        for (int c = 0; c < 4; ++c) {
            sT0 = __builtin_amdgcn_mfma_f32_32x32x16_bf16(kf[0][c], qa[c], sT0, 0, 0, 0);
            sT1 = __builtin_amdgcn_mfma_f32_32x32x16_bf16(kf[1][c], qa[c], sT1, 0, 0, 0);
        }
        __builtin_amdgcn_s_setprio(0);

        // half 0: exp/pack (VALU; sT1 chain still draining in MFMA pipe)
        {
            float pe[16];
#pragma unroll
            for (int ii = 0; ii < 16; ++ii) pe[ii] = EXP2(sT0[ii]);
#pragma unroll
            for (int g = 0; g < 4; ++g)
                Lacc += (pe[4 * g + 0] + pe[4 * g + 1]) +
                        (pe[4 * g + 2] + pe[4 * g + 3]);
            unsigned int W0 = packpair(pe[0],  pe[1]);
            unsigned int W1 = packpair(pe[2],  pe[3]);
            unsigned int W2 = packpair(pe[4],  pe[5]);
            unsigned int W3 = packpair(pe[6],  pe[7]);
            unsigned int W4 = packpair(pe[8],  pe[9]);
            unsigned int W5 = packpair(pe[10], pe[11]);
            unsigned int W6 = packpair(pe[12], pe[13]);
            unsigned int W7 = packpair(pe[14], pe[15]);
            asm volatile("v_permlane32_swap_b32 %0, %1" : "+v"(W0), "+v"(W2));
            asm volatile("v_permlane32_swap_b32 %0, %1" : "+v"(W1), "+v"(W3));
            asm volatile("v_permlane32_swap_b32 %0, %1" : "+v"(W4), "+v"(W6));
            asm volatile("v_permlane32_swap_b32 %0, %1" : "+v"(W5), "+v"(W7));
            union FU { unsigned int u[4]; short8 s; } f0, f1;
            f0.u[0] = W0; f0.u[1] = W1; f0.u[2] = W2; f0.u[3] = W3;
            f1.u[0] = W4; f1.u[1] = W5; f1.u[2] = W6; f1.u[3] = W7;
            // PV half0 into the 'a' accumulators (chains independent of 'b')
            __builtin_amdgcn_s_setprio(1);
            O0a = __builtin_amdgcn_mfma_f32_32x32x16_bf16(vA[0][0], f0.s, O0a, 0, 0, 0);
            O1a = __builtin_amdgcn_mfma_f32_32x32x16_bf16(vA[0][1], f0.s, O1a, 0, 0, 0);
            O0a = __builtin_amdgcn_mfma_f32_32x32x16_bf16(vA[0][2], f1.s, O0a, 0, 0, 0);
            O1a = __builtin_amdgcn_mfma_f32_32x32x16_bf16(vA[0][3], f1.s, O1a, 0, 0, 0);
            __builtin_amdgcn_s_setprio(0);
        }
        // half 1: exp/pack VALU overlaps PV0 drain; PV1 issues immediately
        // (different accumulators -> no scoreboard wait on PV0)
        {
            float pe[16];
#pragma unroll
            for (int ii = 0; ii < 16; ++ii) pe[ii] = EXP2(sT1[ii]);
#pragma unroll
            for (int g = 0; g < 4; ++g)
                Lacc += (pe[4 * g + 0] + pe[4 * g + 1]) +
                        (pe[4 * g + 2] + pe[4 * g + 3]);
            unsigned int W0 = packpair(pe[0],  pe[1]);
            unsigned int W1 = packpair(pe[2],  pe[3]);
            unsigned int W2 = packpair(pe[4],  pe[5]);
            unsigned int W3 = packpair(pe[6],  pe[7]);
            unsigned int W4 = packpair(pe[8],  pe[9]);
            unsigned int W5 = packpair(pe[10], pe[11]);
            unsigned int W6 = packpair(pe[12], pe[13]);
            unsigned int W7 = packpair(pe[14], pe[15]);
            asm volatile("v_permlane32_swap_b32 %0, %1" : "+v"(W0), "+v"(W2));
            asm volatile("v_permlane32_swap_b32 %0, %1" : "+v"(W1), "+v"(W3));
            asm volatile("v_permlane32_swap_b32 %0, %1" : "+v"(W4), "+v"(W6));
            asm volatile("v_permlane32_swap_b32 %0, %1" : "+v"(W5), "+v"(W7));
            union FU { unsigned int u[4]; short8 s; } f0, f1;
            f0.u[0] = W0; f0.u[1] = W1; f0.u[2] = W2; f0.u[3] = W3;
            f1.u[0] = W4; f1.u[1] = W5; f1.u[2] = W6; f1.u[3] = W7;
            __builtin_amdgcn_s_setprio(1);
            O0b = __builtin_amdgcn_mfma_f32_32x32x16_bf16(vA[1][0], f0.s, O0b, 0, 0, 0);
            O1b = __builtin_amdgcn_mfma_f32_32x32x16_bf16(vA[1][1], f0.s, O1b, 0, 0, 0);
            O0b = __builtin_amdgcn_mfma_f32_32x32x16_bf16(vA[1][2], f1.s, O0b, 0, 0, 0);
            O1b = __builtin_amdgcn_mfma_f32_32x32x16_bf16(vA[1][3], f1.s, O1b, 0, 0, 0);
            __builtin_amdgcn_s_setprio(0);
        }

        prv = cur;
        cur = (cur == 2) ? 0 : cur + 1;
    }
#undef STAGE2

    float Lq = Lacc + __shfl(Lacc, lane ^ 32);
    float inv = 1.f / Lq;

    const int b = bh >> 4, h = bh & 15;
    u16* ab = aob + ((size_t)(b * T_SEQ + qrow0 + qcol)) * 1024 + h * 64;
#pragma unroll
    for (int g2 = 0; g2 < 4; ++g2) {
        int dd = g2 * 8 + hi * 4;
        ushort4 w0, w1;
        w0.x = f2b((O0a[4 * g2 + 0] + O0b[4 * g2 + 0]) * inv);
        w0.y = f2b((O0a[4 * g2 + 1] + O0b[4 * g2 + 1]) * inv);
        w0.z = f2b((O0a[4 * g2 + 2] + O0b[4 * g2 + 2]) * inv);
        w0.w = f2b((O0a[4 * g2 + 3] + O0b[4 * g2 + 3]) * inv);
        w1.x = f2b((O1a[4 * g2 + 0] + O1b[4 * g2 + 0]) * inv);
        w1.y = f2b((O1a[4 * g2 + 1] + O1b[4 * g2 + 1]) * inv);
        w1.z = f2b((O1a[4 * g2 + 2] + O1b[4 * g2 + 2]) * inv);
        w1.w = f2b((O1a[4 * g2 + 3] + O1b[4 * g2 + 3]) * inv);
        *(ushort4*)(ab + dd)      = w0;
        *(ushort4*)(ab + 32 + dd) = w1;
    }
}

// ---------------------------------------------------------------------------
extern "C" void kernel_launch(void* const* d_in, const int* in_sizes, int n_in,
                              void* d_out, int out_size, void* d_ws, size_t ws_size,
                              hipStream_t stream)
{
    const float* x    = (const float*)d_in[0];
    const float* Wqkv = (const float*)d_in[1];
    const float* Wout = (const float*)d_in[2];
    const float* bout = (const float*)d_in[3];
    float* out = (float*)d_out;

    char* w = (char*)d_ws;
    u16* qkvb    = (u16*)(w);                   // 25,165,824  (dead after prep)
    u16* xb      = (u16*)(w + 25165824);        //  8,388,608  (dead after gemm1)
    u16* WqkvT   = (u16*)(w + 33554432);        //  6,291,456  (dead after gemm1)
    u16* WoutT   = (u16*)(w + 39845888);        //  2,097,152
    u16* aob     = (u16*)(w + 41943040);        //  8,388,608
    u16* Qb      = (u16*)(w + 50331648);        //  8,388,608
    u16* Kb      = (u16*)(w + 58720256);        //  8,388,608
    u16* Vimg    = (u16*)(w + 67108864);        //  8,388,608
    float* ctab  = (float*)(w + 75497472);      //    524,288
    float* stab  = (float*)(w + 76021760);      //    524,288

    dim3 blk(256);
    setup_kernel<<<dim3(8704), blk, 0, stream>>>(x, Wqkv, Wout, xb, WqkvT, WoutT, ctab, stab);
    gemm_bt_mfma<1><<<dim3(24, 32), blk, 0, stream>>>(xb, WqkvT, qkvb, nullptr, 4096, 3072, 1024);
    prep_kernel<<<dim3(32, 32), blk, 0, stream>>>(qkvb, ctab, stab, Qb, Kb, Vimg);
    attn32_kernel<<<dim3(512), blk, 0, stream>>>(Qb, Kb, Vimg, aob);
    gemm_bt_mfma<0><<<dim3(8, 32), blk, 0, stream>>>(aob, WoutT, out, bout, 4096, 1024, 1024);
}

// Round 15
// 180.066 us; speedup vs baseline: 1.1769x; 1.0340x over previous
//
#include <hip/hip_runtime.h>
#include <math.h>

// B=2, T=2048, DIM=1024, H=16, HD=64. Inputs fp32, output fp32.
// R11-R20: attn rebuilt (Vimg, VALU L-row, counted-vmcnt 3-parity pipeline,
// XCD swizzle, K=16 PV via permlane32_swap, direct bf16 out); GEMM got the
// pipeline + LDS-bounce epilogue. 223 -> 186us.
// R24: 64-key rounds flat; R25: chain-broken MFMA slightly worse (50.0) ->
// attn's 48us is schedule-robust; its MFMA-busy (13.8us) = dense-peak
// minimum for 34.4 GFLOP; VALU-busy 18.8us is the real floor term.
// R26 (orthogonal): fuse prep into gemm1's epilogue. gemm1 already LDS-
// bounces its output; prep re-read that data from HBM (25MB), roped, and
// wrote 25MB back. Now: raw bf16 acc -> Cs; copy phase routes by n0:
//   Q/K tiles: thread owns one head-row (64 contig d) -> rope+scale in-reg
//     (pairs thread-local), 128B write to Qb/Kb;
//   V tiles: prep's exact Vimg permutation with Vls := Cs.
// Kills prep launch + 50MB of qkvb round-trip. attn reverted to R24 body.

typedef unsigned short u16;
typedef __attribute__((ext_vector_type(8))) short short8;
typedef __attribute__((ext_vector_type(4))) short short4v;
typedef __attribute__((ext_vector_type(4))) float f32x4;
typedef __attribute__((ext_vector_type(16))) float f32x16;

#define T_SEQ 2048

#if __has_builtin(__builtin_amdgcn_exp2f)
#define EXP2(x) __builtin_amdgcn_exp2f(x)
#else
#define EXP2(x) exp2f(x)
#endif

__device__ __forceinline__ float b2f(u16 u) {
    union { unsigned int i; float f; } x; x.i = ((unsigned int)u) << 16; return x.f;
}
__device__ __forceinline__ u16 f2b(float f) {
    union { float f; unsigned int i; } x; x.f = f;
    return (u16)((x.i + 0x7FFFu + ((x.i >> 16) & 1u)) >> 16);  // RNE
}
__device__ __forceinline__ void gl_lds16(const u16* g, u16* l) {
    __builtin_amdgcn_global_load_lds(
        (const __attribute__((address_space(1))) unsigned int*)g,
        (__attribute__((address_space(3))) unsigned int*)l, 16, 0, 0);
}
// pack 2 fp32 -> 1 u32 of 2 bf16 (truncation; tiny bias, verified absmax ok)
__device__ __forceinline__ unsigned int packpair(float a, float b) {
    union { float f; unsigned int u; } xa, xb; xa.f = a; xb.f = b;
    return (xa.u >> 16) | (xb.u & 0xffff0000u);
}

// ---------------------------------------------------------------------------
// Fused setup: [0,4096) cast x->bf16; [4096,7168) transpose Wqkv;
// [7168,8192) transpose Wout; [8192,8704) rope table.
// ---------------------------------------------------------------------------
__global__ __launch_bounds__(256) void setup_kernel(
    const float* __restrict__ x, const float* __restrict__ Wqkv,
    const float* __restrict__ Wout, u16* __restrict__ xb,
    u16* __restrict__ WqkvT, u16* __restrict__ WoutT,
    float* __restrict__ costab, float* __restrict__ sintab)
{
    const int bid = blockIdx.x;
    const int tid = threadIdx.x;

    if (bid < 4096) {
        int i = (bid * 256 + tid) * 4;
        float4 v = *(const float4*)(x + i);
        ushort4 w;
        w.x = f2b(v.x); w.y = f2b(v.y); w.z = f2b(v.z); w.w = f2b(v.w);
        *(ushort4*)(xb + i) = w;
        return;
    }
    if (bid < 8192) {
        const float* in; u16* out; int R, Cn, bx, by;
        if (bid < 7168) { in = Wqkv; out = WqkvT; R = 1024; Cn = 3072;
                          int id = bid - 4096; bx = id % 96; by = id / 96; }
        else            { in = Wout; out = WoutT; R = 1024; Cn = 1024;
                          int id = bid - 7168; bx = id & 31; by = id >> 5; }
        __shared__ u16 tile[32][33];
        const int tx = tid & 31, ty = tid >> 5;
        const int r0 = by * 32, c0 = bx * 32;
#pragma unroll
        for (int rr = ty; rr < 32; rr += 8)
            tile[tx][rr] = f2b(in[(size_t)(r0 + rr) * Cn + c0 + tx]);
        __syncthreads();
#pragma unroll
        for (int rr = ty; rr < 32; rr += 8)
            out[(size_t)(c0 + rr) * R + r0 + tx] = tile[rr][tx];
        return;
    }
    {
        int idx = (bid - 8192) * 256 + tid;
        int t = idx >> 6, d = idx & 63;
        const float nl32 = -0.28782313662425576f;   // -ln(10000)/32
        float f = __expf((float)(d & 31) * nl32);
        float s, c;
        __sincosf((float)t * f, &s, &c);
        costab[idx] = c; sintab[idx] = s;
    }
}

// ---------------------------------------------------------------------------
// MFMA GEMM, counted-vmcnt 3-parity pipeline: C[M,N] = A @ Bt^T (+bias).
// OBF=0: fp32 out direct. OBF=1: bf16 out via LDS-bounce coalesced epilogue.
// OBF=2 (R26): fused QKV epilogue -- raw bf16 acc -> Cs, then route by n0:
//   n0<2048: Q/K rope+scale per head-row -> Qb/Kb;  n0>=2048: Vimg permute.
// ---------------------------------------------------------------------------
template<int OBF>
__global__ __launch_bounds__(256) void gemm_bt_mfma(
    const u16* __restrict__ A, const u16* __restrict__ Bt,
    void* __restrict__ Cv, const float* __restrict__ bias,
    int M, int N, int K,
    const float* __restrict__ ctab, const float* __restrict__ stab,
    u16* __restrict__ Qb, u16* __restrict__ Kb, u16* __restrict__ Vimg)
{
    __shared__ u16 sbuf[24576];   // 48 KB: As parities [0,12288), Bs [12288,24576)
    u16* const As0 = sbuf;
    u16* const Bs0 = sbuf + 12288;

    const int tid = threadIdx.x;
    const int wave = tid >> 6, lane = tid & 63;
    const int col = lane & 15, quad = lane >> 4;
    const int wm = (wave & 1) * 64, wn = (wave >> 1) * 64;
    const int m0 = blockIdx.y * 128, n0 = blockIdx.x * 128;

    f32x4 acc[4][4];
#pragma unroll
    for (int i = 0; i < 4; ++i)
#pragma unroll
        for (int j = 0; j < 4; ++j) acc[i][j] = f32x4{0.f, 0.f, 0.f, 0.f};

    const int c1 = tid, c2 = tid + 256;
    const u16* a1 = A + (size_t)(m0 + (c1 >> 2)) * K + (c1 & 3) * 8;
    const u16* a2 = A + (size_t)(m0 + (c2 >> 2)) * K + (c2 & 3) * 8;
    const u16* b1 = Bt + (size_t)(n0 + (c1 >> 2)) * K + (c1 & 3) * 8;
    const u16* b2 = Bt + (size_t)(n0 + (c2 >> 2)) * K + (c2 & 3) * 8;
    const int l1 = c1 * 8, l2 = c2 * 8;

#define GST(p, ks) do { const int k0_ = (ks) * 32;                            \
        gl_lds16(a1 + k0_, As0 + (p) * 4096 + l1);                            \
        gl_lds16(a2 + k0_, As0 + (p) * 4096 + l2);                            \
        gl_lds16(b1 + k0_, Bs0 + (p) * 4096 + l1);                            \
        gl_lds16(b2 + k0_, Bs0 + (p) * 4096 + l2);                            \
    } while (0)

    const int NK = K >> 5;
    // prologue: k-steps 0,1 in flight (8 DMAs/wave)
    GST(0, 0);
    GST(1, 1);

    int cur = 0, prv = 2;
    for (int ks = 0; ks < NK; ++ks) {
        // own k-step's 4 DMAs landed (oldest); next step's 4 stay in flight
        if (ks < NK - 1) asm volatile("s_waitcnt vmcnt(4)" ::: "memory");
        else             asm volatile("s_waitcnt vmcnt(0)" ::: "memory");
        __builtin_amdgcn_s_barrier();
        asm volatile("" ::: "memory");          // compiler fence
        __builtin_amdgcn_sched_barrier(0);      // rule #18: pin MIR scheduler

        // (1) read-first: pull fragments from parity cur
        short8 af[4], bfr[4];
        const u16* Ap = As0 + cur * 4096;
        const u16* Bp = Bs0 + cur * 4096;
#pragma unroll
        for (int i = 0; i < 4; ++i) {
            af[i]  = *(const short8*)&Ap[(wm + i * 16 + col) * 32 + quad * 8];
            bfr[i] = *(const short8*)&Bp[(wn + i * 16 + col) * 32 + quad * 8];
        }

        // (2) stage k-step ks+2 into parity prv (freed by this barrier)
        if (ks < NK - 2) GST(prv, ks + 2);

        // (3) register-only MFMA
        __builtin_amdgcn_s_setprio(1);
#pragma unroll
        for (int i = 0; i < 4; ++i)
#pragma unroll
            for (int j = 0; j < 4; ++j)
                acc[i][j] = __builtin_amdgcn_mfma_f32_16x16x32_bf16(
                    af[i], bfr[j], acc[i][j], 0, 0, 0);
        __builtin_amdgcn_s_setprio(0);

        prv = cur;
        cur = (cur == 2) ? 0 : cur + 1;
    }
#undef GST

    if (OBF == 0) {
        // fp32 out: direct stores (64B per 16 lanes, line-friendly) + bias
#pragma unroll
        for (int j = 0; j < 4; ++j) {
            int n = n0 + wn + j * 16 + col;
            float bv = bias ? bias[n] : 0.f;
#pragma unroll
            for (int i = 0; i < 4; ++i) {
                int mbase = m0 + wm + i * 16 + quad * 4;
#pragma unroll
                for (int r = 0; r < 4; ++r)
                    ((float*)Cv)[(size_t)(mbase + r) * N + n] = acc[i][j][r] + bv;
            }
        }
        return;
    }

    // OBF 1/2: bounce acc through LDS ([128][136] u16; 272B stride = 17*16
    // keeps b128 aligned and breaks power-of-2 bank aliasing).
    __syncthreads();
    u16* Cs = sbuf;   // 128*136*2 = 34816 B of the 48 KB
#pragma unroll
    for (int j = 0; j < 4; ++j) {
        const int cl = wn + j * 16 + col;
        const float bv = (OBF == 1 && bias) ? bias[n0 + cl] : 0.f;
#pragma unroll
        for (int i = 0; i < 4; ++i) {
            const int rl = wm + i * 16 + quad * 4;
#pragma unroll
            for (int r = 0; r < 4; ++r)
                Cs[(rl + r) * 136 + cl] = f2b(acc[i][j][r] + bv);
        }
    }
    __syncthreads();

    if (OBF == 1) {
        // plain bf16 row-major out: thread t owns row=t>>1, half=t&1 (128B)
        const int row = tid >> 1, half = tid & 1;
        const u16* src = Cs + row * 136 + half * 64;
        u16* dst = (u16*)Cv + (size_t)(m0 + row) * N + n0 + half * 64;
#pragma unroll
        for (int s = 0; s < 8; ++s)
            *(short8*)(dst + s * 8) = *(const short8*)(src + s * 8);
        return;
    }

    // OBF == 2: fused QKV routing epilogue
    if (n0 < 2048) {
        // Q or K tile: thread owns one full head-row (64 contiguous d)
        const int row = tid >> 1, half = tid & 1;
        const int tt = m0 + row;
        const int b = tt >> 11, t = tt & 2047;
        const int gcol = n0 + half * 64;
        const int isQ = (gcol < 1024) ? 1 : 0;
        const int h = (isQ ? gcol : (gcol - 1024)) >> 6;
        const float sc = isQ ? 0.18033688011112042f : 1.f;   // 0.125*log2(e)
        const u16* src = Cs + row * 136 + half * 64;
        u16* dst = (isQ ? Qb : Kb) + ((size_t)((b * 16 + h) * T_SEQ + t)) * 64;
        const float* cp = ctab + (size_t)t * 64;
        const float* sp = stab + (size_t)t * 64;
#pragma unroll
        for (int c4 = 0; c4 < 4; ++c4) {
            short8 v0 = *(const short8*)(src + c4 * 16);
            short8 v1 = *(const short8*)(src + c4 * 16 + 8);
            float f[16], ct4[16], st4[16];
#pragma unroll
            for (int jj = 0; jj < 8; ++jj) {
                f[jj] = b2f((u16)v0[jj]); f[8 + jj] = b2f((u16)v1[jj]);
            }
#pragma unroll
            for (int jj = 0; jj < 16; jj += 4) {
                *(float4*)&ct4[jj] = *(const float4*)(cp + c4 * 16 + jj);
                *(float4*)&st4[jj] = *(const float4*)(sp + c4 * 16 + jj);
            }
            u16 o[16];
#pragma unroll
            for (int i2 = 0; i2 < 8; ++i2) {
                float e = f[2 * i2], od = f[2 * i2 + 1];
                o[2 * i2]     = f2b((e * ct4[2 * i2]      - od * st4[2 * i2]) * sc);
                o[2 * i2 + 1] = f2b((od * ct4[2 * i2 + 1] + e  * st4[2 * i2 + 1]) * sc);
            }
            *(short8*)(dst + c4 * 16)     = *(short8*)&o[0];
            *(short8*)(dst + c4 * 16 + 8) = *(short8*)&o[8];
        }
    } else {
        // V tile: prep's Vimg permutation with Vls := Cs (rows = 4 key-panels
        // of 32 tokens; cols = 2 heads x 64 d). Per (panel, head): each of
        // 256 threads gathers 8 u16 and writes one short8 to its slot.
        const int b = m0 >> 11;
        const int h0 = (n0 - 2048) >> 6;
        const int ktb = (m0 & 2047) >> 5;
        const int m_ = (tid >> 7) & 1;
        const int db = (tid >> 6) & 1;
        const int h2 = (tid >> 5) & 1;
        const int dv = tid & 31;
        const int k0v = m_ * 16 + h2 * 8;
#pragma unroll
        for (int ph = 0; ph < 8; ++ph) {
            const int panel = ph >> 1, hh = ph & 1;
            const int bh = b * 16 + h0 + hh;
            const int dcol = hh * 64 + db * 32 + dv;
            u16 o[8];
#pragma unroll
            for (int jj = 0; jj < 8; ++jj)
                o[jj] = Cs[(panel * 32 + k0v + jj) * 136 + dcol];
            u16* dst = Vimg + ((size_t)(bh * 64 + ktb + panel)) * 2048 + tid * 8;
            *(short8*)dst = *(short8*)&o[0];
        }
    }
}

// ---------------------------------------------------------------------------
// MFMA flash attention (R24 body -- fastest measured at 48.3us): counted-
// vmcnt 3-parity pipeline, 64-key rounds (2 tiles/round, 32 rounds), K=16 PV
// via permlane32_swap, grid 512 XCD-swizzled, direct bf16 epilogue -> aob.
// ---------------------------------------------------------------------------
__global__ __launch_bounds__(256, 2) void attn32_kernel(
    const u16* __restrict__ Qb, const u16* __restrict__ Kb,
    const u16* __restrict__ Vimg, u16* __restrict__ aob)
{
    __shared__ u16 Kbuf[3][2][2048];   // [parity][half][tile]  24 KB
    __shared__ u16 Vbuf[3][2][2048];   // 24 KB

    const int tid = threadIdx.x;
    const int wave = tid >> 6, lane = tid & 63;
    const int qcol = lane & 31;
    const int hi = lane >> 5;

    const int bid = blockIdx.x;
    const int lbid = (bid & 7) * 64 + (bid >> 3);
    const int bh = lbid >> 4;
    const int qblk = lbid & 15;
    const int qrow0 = qblk * 128 + wave * 32;

    // Q B-frags (32x32x16): lane(n=q, hi): Q[q][c*16 + hi*8 + j]
    short8 qa[4];
    {
        const u16* qp = Qb + ((size_t)(bh * T_SEQ + qrow0 + qcol)) * 64 + hi * 8;
#pragma unroll
        for (int c = 0; c < 4; ++c) qa[c] = *(const short8*)(qp + c * 16);
    }

    f32x16 O0, O1;
#pragma unroll
    for (int i = 0; i < 16; ++i) { O0[i] = 0.f; O1[i] = 0.f; }
    float Lacc = 0.f;

    const u16* kg_ptr = Kb + ((size_t)bh * T_SEQ + qcol) * 64 + wave * 16 + hi * 8;
    const u16* vg_ptr = Vimg + ((size_t)bh * 64) * 2048 + tid * 8;

#define STAGE2(p, rr) do {                                                    \
        gl_lds16(kg_ptr + (size_t)(2 * (rr))     * 2048, &Kbuf[p][0][tid * 8]);\
        gl_lds16(kg_ptr + (size_t)(2 * (rr) + 1) * 2048, &Kbuf[p][1][tid * 8]);\
        gl_lds16(vg_ptr + (size_t)(2 * (rr))     * 2048, &Vbuf[p][0][tid * 8]);\
        gl_lds16(vg_ptr + (size_t)(2 * (rr) + 1) * 2048, &Vbuf[p][1][tid * 8]);\
    } while (0)

    // prologue: rounds 0,1 in flight (8 DMAs/wave)
    STAGE2(0, 0);
    STAGE2(1, 1);

    int cur = 0, prv = 2;
    for (int r = 0; r < 32; ++r) {
        if (r < 31) asm volatile("s_waitcnt vmcnt(4)" ::: "memory");
        else        asm volatile("s_waitcnt vmcnt(0)" ::: "memory");
        __builtin_amdgcn_s_barrier();
        asm volatile("" ::: "memory");          // compiler fence
        __builtin_amdgcn_sched_barrier(0);      // rule #18

        // (1) read-first: both halves' K/V fragments into registers
        short8 kf[2][4], vA[2][4];
#pragma unroll
        for (int half = 0; half < 2; ++half) {
#pragma unroll
            for (int f = 0; f < 4; ++f)
                kf[half][f] = *(const short8*)&Kbuf[cur][half][(f * 64 + lane) * 8];
#pragma unroll
            for (int rg = 0; rg < 4; ++rg)
                vA[half][rg] = *(const short8*)&Vbuf[cur][half][rg * 512 + lane * 8];
        }

        // (2) stage round r+2 into parity prv (freed by this barrier)
        if (r < 30) STAGE2(prv, r + 2);

        // (3) QK both halves back-to-back
        f32x16 sT0, sT1;
#pragma unroll
        for (int ii = 0; ii < 16; ++ii) { sT0[ii] = 0.f; sT1[ii] = 0.f; }
        __builtin_amdgcn_s_setprio(1);
#pragma unroll
        for (int c = 0; c < 4; ++c)
            sT0 = __builtin_amdgcn_mfma_f32_32x32x16_bf16(kf[0][c], qa[c], sT0, 0, 0, 0);
#pragma unroll
        for (int c = 0; c < 4; ++c)
            sT1 = __builtin_amdgcn_mfma_f32_32x32x16_bf16(kf[1][c], qa[c], sT1, 0, 0, 0);
        __builtin_amdgcn_s_setprio(0);

        // half 0: exp/pack (VALU) then PV (MFMA)
        {
            float pe[16];
#pragma unroll
            for (int ii = 0; ii < 16; ++ii) pe[ii] = EXP2(sT0[ii]);
#pragma unroll
            for (int g = 0; g < 4; ++g)
                Lacc += (pe[4 * g + 0] + pe[4 * g + 1]) +
                        (pe[4 * g + 2] + pe[4 * g + 3]);
            unsigned int W0 = packpair(pe[0],  pe[1]);
            unsigned int W1 = packpair(pe[2],  pe[3]);
            unsigned int W2 = packpair(pe[4],  pe[5]);
            unsigned int W3 = packpair(pe[6],  pe[7]);
            unsigned int W4 = packpair(pe[8],  pe[9]);
            unsigned int W5 = packpair(pe[10], pe[11]);
            unsigned int W6 = packpair(pe[12], pe[13]);
            unsigned int W7 = packpair(pe[14], pe[15]);
            asm volatile("v_permlane32_swap_b32 %0, %1" : "+v"(W0), "+v"(W2));
            asm volatile("v_permlane32_swap_b32 %0, %1" : "+v"(W1), "+v"(W3));
            asm volatile("v_permlane32_swap_b32 %0, %1" : "+v"(W4), "+v"(W6));
            asm volatile("v_permlane32_swap_b32 %0, %1" : "+v"(W5), "+v"(W7));
            union FU { unsigned int u[4]; short8 s; } f0, f1;
            f0.u[0] = W0; f0.u[1] = W1; f0.u[2] = W2; f0.u[3] = W3;
            f1.u[0] = W4; f1.u[1] = W5; f1.u[2] = W6; f1.u[3] = W7;
            __builtin_amdgcn_s_setprio(1);
            O0 = __builtin_amdgcn_mfma_f32_32x32x16_bf16(vA[0][0], f0.s, O0, 0, 0, 0);
            O1 = __builtin_amdgcn_mfma_f32_32x32x16_bf16(vA[0][1], f0.s, O1, 0, 0, 0);
            O0 = __builtin_amdgcn_mfma_f32_32x32x16_bf16(vA[0][2], f1.s, O0, 0, 0, 0);
            O1 = __builtin_amdgcn_mfma_f32_32x32x16_bf16(vA[0][3], f1.s, O1, 0, 0, 0);
            __builtin_amdgcn_s_setprio(0);
        }
        // half 1
        {
            float pe[16];
#pragma unroll
            for (int ii = 0; ii < 16; ++ii) pe[ii] = EXP2(sT1[ii]);
#pragma unroll
            for (int g = 0; g < 4; ++g)
                Lacc += (pe[4 * g + 0] + pe[4 * g + 1]) +
                        (pe[4 * g + 2] + pe[4 * g + 3]);
            unsigned int W0 = packpair(pe[0],  pe[1]);
            unsigned int W1 = packpair(pe[2],  pe[3]);
            unsigned int W2 = packpair(pe[4],  pe[5]);
            unsigned int W3 = packpair(pe[6],  pe[7]);
            unsigned int W4 = packpair(pe[8],  pe[9]);
            unsigned int W5 = packpair(pe[10], pe[11]);
            unsigned int W6 = packpair(pe[12], pe[13]);
            unsigned int W7 = packpair(pe[14], pe[15]);
            asm volatile("v_permlane32_swap_b32 %0, %1" : "+v"(W0), "+v"(W2));
            asm volatile("v_permlane32_swap_b32 %0, %1" : "+v"(W1), "+v"(W3));
            asm volatile("v_permlane32_swap_b32 %0, %1" : "+v"(W4), "+v"(W6));
            asm volatile("v_permlane32_swap_b32 %0, %1" : "+v"(W5), "+v"(W7));
            union FU { unsigned int u[4]; short8 s; } f0, f1;
            f0.u[0] = W0; f0.u[1] = W1; f0.u[2] = W2; f0.u[3] = W3;
            f1.u[0] = W4; f1.u[1] = W5; f1.u[2] = W6; f1.u[3] = W7;
            __builtin_amdgcn_s_setprio(1);
            O0 = __builtin_amdgcn_mfma_f32_32x32x16_bf16(vA[1][0], f0.s, O0, 0, 0, 0);
            O1 = __builtin_amdgcn_mfma_f32_32x32x16_bf16(vA[1][1], f0.s, O1, 0, 0, 0);
            O0 = __builtin_amdgcn_mfma_f32_32x32x16_bf16(vA[1][2], f1.s, O0, 0, 0, 0);
            O1 = __builtin_amdgcn_mfma_f32_32x32x16_bf16(vA[1][3], f1.s, O1, 0, 0, 0);
            __builtin_amdgcn_s_setprio(0);
        }

        prv = cur;
        cur = (cur == 2) ? 0 : cur + 1;
    }
#undef STAGE2

    float Lq = Lacc + __shfl(Lacc, lane ^ 32);
    float inv = 1.f / Lq;

    const int b = bh >> 4, h = bh & 15;
    u16* ab = aob + ((size_t)(b * T_SEQ + qrow0 + qcol)) * 1024 + h * 64;
#pragma unroll
    for (int g2 = 0; g2 < 4; ++g2) {
        int dd = g2 * 8 + hi * 4;
        ushort4 w0, w1;
        w0.x = f2b(O0[4 * g2 + 0] * inv); w0.y = f2b(O0[4 * g2 + 1] * inv);
        w0.z = f2b(O0[4 * g2 + 2] * inv); w0.w = f2b(O0[4 * g2 + 3] * inv);
        w1.x = f2b(O1[4 * g2 + 0] * inv); w1.y = f2b(O1[4 * g2 + 1] * inv);
        w1.z = f2b(O1[4 * g2 + 2] * inv); w1.w = f2b(O1[4 * g2 + 3] * inv);
        *(ushort4*)(ab + dd)      = w0;
        *(ushort4*)(ab + 32 + dd) = w1;
    }
}

// ---------------------------------------------------------------------------
extern "C" void kernel_launch(void* const* d_in, const int* in_sizes, int n_in,
                              void* d_out, int out_size, void* d_ws, size_t ws_size,
                              hipStream_t stream)
{
    const float* x    = (const float*)d_in[0];
    const float* Wqkv = (const float*)d_in[1];
    const float* Wout = (const float*)d_in[2];
    const float* bout = (const float*)d_in[3];
    float* out = (float*)d_out;

    char* w = (char*)d_ws;
    u16* xb      = (u16*)(w + 25165824);        //  8,388,608  (dead after gemm1)
    u16* WqkvT   = (u16*)(w + 33554432);        //  6,291,456  (dead after gemm1)
    u16* WoutT   = (u16*)(w + 39845888);        //  2,097,152
    u16* aob     = (u16*)(w + 41943040);        //  8,388,608
    u16* Qb      = (u16*)(w + 50331648);        //  8,388,608
    u16* Kb      = (u16*)(w + 58720256);        //  8,388,608
    u16* Vimg    = (u16*)(w + 67108864);        //  8,388,608
    float* ctab  = (float*)(w + 75497472);      //    524,288
    float* stab  = (float*)(w + 76021760);      //    524,288
    // [0, 25165824) region (old qkvb) now unused -- prep fused into gemm1.

    dim3 blk(256);
    setup_kernel<<<dim3(8704), blk, 0, stream>>>(x, Wqkv, Wout, xb, WqkvT, WoutT, ctab, stab);
    gemm_bt_mfma<2><<<dim3(24, 32), blk, 0, stream>>>(
        xb, WqkvT, nullptr, nullptr, 4096, 3072, 1024, ctab, stab, Qb, Kb, Vimg);
    attn32_kernel<<<dim3(512), blk, 0, stream>>>(Qb, Kb, Vimg, aob);
    gemm_bt_mfma<0><<<dim3(8, 32), blk, 0, stream>>>(
        aob, WoutT, out, bout, 4096, 1024, 1024, nullptr, nullptr, nullptr, nullptr, nullptr);
}